// Round 10
// baseline (208.286 us; speedup 1.0000x reference)
//
#include <hip/hip_runtime.h>
#include <hip/hip_bf16.h>
#include <math.h>

// B=16, S=1024, CC=8, CF=8, E=64, H=1024, NH=16, DH=64, VOCAB=10000
// Output = out[:, -1:, -1] -> 16 f32
// Attention algebra: only query S-1 is needed. y[b,h,k]=x'_k.wvo_h folded into
// score; final LN(xb) folded algebraically (stats via MFMA in score_k, inline
// in qk_k). Round 9's pre-gather reverted (+4us, gather wasn't the cost).
// This round: qproj+kq fused into qk_k (grid 64, Q computed 4x redundantly
// in-block) -- one fewer dispatch boundary + no qpart round-trip.
// GEMMs frozen at round-3 form (72.0us, VGPR 116; round-5 regalloc lesson).
#define EPS 1e-5f

typedef unsigned short u16;
typedef __attribute__((ext_vector_type(8))) short bf16x8;
typedef __attribute__((ext_vector_type(4))) float f32x4;

__device__ __forceinline__ float b2f(u16 u) {
  union { unsigned int i; float f; } v; v.i = ((unsigned int)u) << 16; return v.f;
}
__device__ __forceinline__ u16 f2b(float f) {
  union { float f; unsigned int i; } v; v.f = f;
  unsigned int r = v.i + 0x7fff + ((v.i >> 16) & 1);
  return (u16)(r >> 16);
}

__device__ __forceinline__ void gload_lds16(const u16* g, u16* l) {
  __builtin_amdgcn_global_load_lds(
      (const __attribute__((address_space(1))) unsigned int*)g,
      (__attribute__((address_space(3))) unsigned int*)l, 16, 0, 0);
}

// ---------------- preprocessing needed BEFORE gemm1 -----------------------------
__global__ __launch_bounds__(256) void prep_k(
    const float* __restrict__ cx, float* __restrict__ part_bn,
    float* __restrict__ out, float* __restrict__ Sall,
    const float* __restrict__ emb, u16* __restrict__ embb,
    const float* __restrict__ cate_W, u16* __restrict__ cateWT) {
  __shared__ float shmem[64 * 65];
  const int bid = blockIdx.x, tid = threadIdx.x;

  if (bid == 0) {
    if (tid < 16) out[tid] = 0.f;                        // d_out accumulator
    for (int i = tid; i < 544; i += 256) Sall[i] = 0.f;  // Sg|Sb|Swg|Swb
    return;
  }
  if (bid <= 64) {                       // BN partial sums
    int pb = bid - 1;
    int gid = pb * 256 + tid;
    float4 a = ((const float4*)cx)[2 * gid];
    float4 b = ((const float4*)cx)[2 * gid + 1];
    float v[16];
    v[0] = a.x; v[1] = a.y; v[2] = a.z; v[3] = a.w;
    v[4] = b.x; v[5] = b.y; v[6] = b.z; v[7] = b.w;
#pragma unroll
    for (int i = 0; i < 8; ++i) v[8 + i] = v[i] * v[i];
#pragma unroll
    for (int off = 32; off; off >>= 1)
#pragma unroll
      for (int i = 0; i < 16; ++i) v[i] += __shfl_down(v[i], off);
    int l = tid & 63, wv_ = tid >> 6;
    if (l == 0)
#pragma unroll
      for (int i = 0; i < 16; ++i) shmem[wv_ * 16 + i] = v[i];
    __syncthreads();
    if (tid < 16)
      part_bn[pb * 16 + tid] = shmem[tid] + shmem[16 + tid] + shmem[32 + tid] + shmem[48 + tid];
    return;
  }
  if (bid <= 689) {                      // embconv
    int i = (bid - 65) * 256 + tid;
    if (i < 160000) {
      float4 v = ((const float4*)emb)[i];
      ushort4 u; u.x = f2b(v.x); u.y = f2b(v.y); u.z = f2b(v.z); u.w = f2b(v.w);
      ((ushort4*)embb)[i] = u;
    }
    return;
  }
  {                                      // cateWT transpose fp32->bf16 (K=512)
    int local = bid - 690;
    int n0 = (local & 15) * 64, k0 = (local >> 4) * 64;
    int c = tid & 63, r0 = tid >> 6;
#pragma unroll
    for (int i = 0; i < 16; ++i) {
      int r = r0 + i * 4;
      shmem[r * 65 + c] = cate_W[(size_t)(k0 + r) * 1024 + n0 + c];
    }
    __syncthreads();
#pragma unroll
    for (int i = 0; i < 16; ++i) {
      int r = r0 + i * 4;
      cateWT[(size_t)(n0 + r) * 512 + k0 + c] = f2b(shmem[c * 65 + r]);
    }
  }
}

// ---------------- 256x256 MFMA GEMM, 8 waves, BK=64, 8-phase schedule -----------
// FROZEN round-3 kernel (72.0us, VGPR 116): XCD-chunked swizzle, 8-phase
// counted-vmcnt, MODE-1 sidx stash. No epilogue additions (round-5 lesson).
template <int MODE>
__global__ __launch_bounds__(512) void gemm256(
    const u16* __restrict__ A0, const u16* __restrict__ A1,
    const int* __restrict__ idx, const u16* __restrict__ embb,
    const u16* __restrict__ BT, const float* __restrict__ bias,
    u16* __restrict__ C, int K) {
  __shared__ u16 As[2][2][8192];
  __shared__ u16 Bs[2][2][8192];
  __shared__ int sidx[MODE == 1 ? 2048 : 4];
  const int tid = threadIdx.x;
  const int bid = blockIdx.x;
  const int chunk = gridDim.x >> 3;               // 32
  const int swz = (bid & 7) * chunk + (bid >> 3); // XCD-chunked, bijective
  const int row0 = (swz >> 2) * 256;
  const int col0 = (swz & 3) * 256;

  const int rr8 = tid >> 3;
  const int p8  = tid & 7;
  const int sl  = p8 ^ (rr8 & 7);

  const int l   = tid & 63;
  const int w   = tid >> 6;
  const int wrh = w >> 2;
  const int wcq = w & 3;
  const int hb  = wcq >> 1;
  const int rbb = (wcq & 1) * 64;
  const int lr  = l & 15;
  const int lk  = l >> 4;

  f32x4 acc[8][4];
#pragma unroll
  for (int m = 0; m < 8; ++m)
#pragma unroll
    for (int n = 0; n < 4; ++n) acc[m][n] = (f32x4){0.f, 0.f, 0.f, 0.f};

  const int nt = K >> 6;        // 8 (cate) or 32 (comb) -- always even
  const int nit = nt >> 1;

  if (MODE == 1) {              // stash all 256 rows x 8 k-chunk indices in LDS
    *(int4*)&sidx[tid * 4] = *(const int4*)&idx[row0 * 8 + tid * 4];
    __syncthreads();
  }

  auto stageA = [&](int t, int h) {               // one A half-tile: 2 loads
    const int k0 = t << 6;
    const int buf = t & 1;
#pragma unroll
    for (int i = 0; i < 2; ++i) {
      const u16* asrc;
      if (MODE == 1) {
        int id = sidx[(h * 128 + i * 64 + rr8) * 8 + (k0 >> 6)];
        asrc = embb + (size_t)id * 64 + sl * 8;
      } else {
        int ar = row0 + h * 128 + i * 64 + rr8;
        const u16* base = (k0 < 1024) ? A0 : A1;
        asrc = base + (size_t)ar * 1024 + (k0 & 1023) + sl * 8;
      }
      gload_lds16(asrc, &As[buf][h][i * 4096 + tid * 8]);
    }
  };
  auto stageB = [&](int t, int h) {               // one B half-tile: 2 loads
    const int k0 = t << 6;
    const int buf = t & 1;
#pragma unroll
    for (int i = 0; i < 2; ++i) {
      int br = col0 + h * 128 + i * 64 + rr8;
      gload_lds16(BT + (size_t)br * K + k0 + sl * 8,
                  &Bs[buf][h][i * 4096 + tid * 8]);
    }
  };

  bf16x8 bfr[4][2];
  auto loadB = [&](int buf) {                     // 8 ds_read_b128
#pragma unroll
    for (int n = 0; n < 4; ++n)
#pragma unroll
      for (int ks = 0; ks < 2; ++ks) {
        int rowb = rbb + n * 16 + lr;
        int ph = (ks * 4 + lk) ^ (lr & 7);
        bfr[n][ks] = *(const bf16x8*)&Bs[buf][hb][rowb * 64 + ph * 8];
      }
  };
  auto loadA = [&](bf16x8 (&af)[2][2], int buf, int q) {  // 4 ds_read_b128
#pragma unroll
    for (int mm = 0; mm < 2; ++mm)
#pragma unroll
      for (int ks = 0; ks < 2; ++ks) {
        int rowa = (q * 2 + mm) * 16 + lr;
        int ph = (ks * 4 + lk) ^ (lr & 7);
        af[mm][ks] = *(const bf16x8*)&As[buf][wrh][rowa * 64 + ph * 8];
      }
  };
  auto mfma_quad = [&](bf16x8 (&af)[2][2], int q) {       // 16 MFMA
    __builtin_amdgcn_s_setprio(1);
#pragma unroll
    for (int ks = 0; ks < 2; ++ks)
#pragma unroll
      for (int mm = 0; mm < 2; ++mm)
#pragma unroll
        for (int n = 0; n < 4; ++n)
          acc[q * 2 + mm][n] = __builtin_amdgcn_mfma_f32_16x16x32_bf16(
              af[mm][ks], bfr[n][ks], acc[q * 2 + mm][n], 0, 0, 0);
    __builtin_amdgcn_s_setprio(0);
  };

  // ---- prologue: tile0 A+B, tile1 B; wait tile0 (leave tile1-B in flight)
  stageA(0, 0); stageA(0, 1);
  stageB(0, 0); stageB(0, 1);
  stageB(1, 0); stageB(1, 1);
  asm volatile("s_waitcnt vmcnt(4)" ::: "memory");
  __builtin_amdgcn_s_barrier();

  for (int it = 0; it < nit; ++it) {
    const int T = it * 2;
    const bool more = (T + 2 < nt);     // also == (T+3 < nt) since nt even
    bf16x8 af[2][2];

    // -------- tile T (buf 0) --------
    loadB(0); loadA(af, 0, 0);
    stageA(T + 1, 0);
    __builtin_amdgcn_s_barrier();
    asm volatile("s_waitcnt lgkmcnt(0)" ::: "memory");
    mfma_quad(af, 0);
    __builtin_amdgcn_s_barrier();
    loadA(af, 0, 1);
    stageA(T + 1, 1);
    __builtin_amdgcn_s_barrier();
    asm volatile("s_waitcnt lgkmcnt(0)" ::: "memory");
    mfma_quad(af, 1);
    __builtin_amdgcn_s_barrier();
    loadA(af, 0, 2);
    if (more) stageB(T + 2, 0);
    __builtin_amdgcn_s_barrier();
    asm volatile("s_waitcnt lgkmcnt(0)" ::: "memory");
    mfma_quad(af, 2);
    __builtin_amdgcn_s_barrier();
    loadA(af, 0, 3);
    if (more) stageB(T + 2, 1);
    __builtin_amdgcn_s_barrier();
    asm volatile("s_waitcnt lgkmcnt(0)" ::: "memory");
    mfma_quad(af, 3);
    if (more) asm volatile("s_waitcnt vmcnt(4)" ::: "memory");
    else      asm volatile("s_waitcnt vmcnt(0)" ::: "memory");
    __builtin_amdgcn_s_barrier();

    // -------- tile T+1 (buf 1) --------
    loadB(1); loadA(af, 1, 0);
    if (more) stageA(T + 2, 0);
    __builtin_amdgcn_s_barrier();
    asm volatile("s_waitcnt lgkmcnt(0)" ::: "memory");
    mfma_quad(af, 0);
    __builtin_amdgcn_s_barrier();
    loadA(af, 1, 1);
    if (more) stageA(T + 2, 1);
    __builtin_amdgcn_s_barrier();
    asm volatile("s_waitcnt lgkmcnt(0)" ::: "memory");
    mfma_quad(af, 1);
    __builtin_amdgcn_s_barrier();
    loadA(af, 1, 2);
    if (more) stageB(T + 3, 0);
    __builtin_amdgcn_s_barrier();
    asm volatile("s_waitcnt lgkmcnt(0)" ::: "memory");
    mfma_quad(af, 2);
    __builtin_amdgcn_s_barrier();
    loadA(af, 1, 3);
    if (more) stageB(T + 3, 1);
    __builtin_amdgcn_s_barrier();
    asm volatile("s_waitcnt lgkmcnt(0)" ::: "memory");
    mfma_quad(af, 3);
    if (it + 1 < nit) {
      asm volatile("s_waitcnt vmcnt(4)" ::: "memory");
      __builtin_amdgcn_s_barrier();
    }
  }

  float bv_[4];
#pragma unroll
  for (int n = 0; n < 4; ++n) bv_[n] = bias[col0 + wcq * 64 + n * 16 + lr];
#pragma unroll
  for (int m = 0; m < 8; ++m) {
#pragma unroll
    for (int n = 0; n < 4; ++n) {
      int cc = col0 + wcq * 64 + n * 16 + lr;
#pragma unroll
      for (int q4 = 0; q4 < 4; ++q4) {
        int rr = row0 + wrh * 128 + m * 16 + lk * 4 + q4;
        C[(size_t)rr * 1024 + cc] = f2b(acc[m][n][q4] + bv_[n]);
      }
    }
  }
}

// ---------------- In-place LayerNorm body (used by mid_k for X1) ----------------
__device__ __forceinline__ void ln_body(u16* __restrict__ buf,
                                        const float* __restrict__ g,
                                        const float* __restrict__ b, int relu,
                                        int blk, int tid) {
  int lane = tid & 63, wave = tid >> 6;
  size_t row = (size_t)blk * 4 + wave;
  u16* p = buf + row * 1024 + lane * 16;
  uint4 u0 = *(uint4*)p;
  uint4 u1 = *(uint4*)(p + 8);
  float x[16];
#pragma unroll
  for (int i = 0; i < 4; ++i) {
    unsigned int w0 = ((unsigned int*)&u0)[i];
    unsigned int w1 = ((unsigned int*)&u1)[i];
    x[2 * i]     = b2f((u16)(w0 & 0xffff));
    x[2 * i + 1] = b2f((u16)(w0 >> 16));
    x[8 + 2 * i]     = b2f((u16)(w1 & 0xffff));
    x[8 + 2 * i + 1] = b2f((u16)(w1 >> 16));
  }
  float s = 0.f, s2 = 0.f;
#pragma unroll
  for (int i = 0; i < 16; ++i) { s += x[i]; s2 += x[i] * x[i]; }
#pragma unroll
  for (int off = 32; off; off >>= 1) { s += __shfl_xor(s, off); s2 += __shfl_xor(s2, off); }
  float mean = s * (1.f / 1024.f);
  float var = s2 * (1.f / 1024.f) - mean * mean;
  float rs = rsqrtf(var + EPS);
  float y[16];
#pragma unroll
  for (int q = 0; q < 4; ++q) {
    float4 gv = *(const float4*)(g + lane * 16 + q * 4);
    float4 bv = *(const float4*)(b + lane * 16 + q * 4);
    y[4 * q]     = (x[4 * q]     - mean) * rs * gv.x + bv.x;
    y[4 * q + 1] = (x[4 * q + 1] - mean) * rs * gv.y + bv.y;
    y[4 * q + 2] = (x[4 * q + 2] - mean) * rs * gv.z + bv.z;
    y[4 * q + 3] = (x[4 * q + 3] - mean) * rs * gv.w + bv.w;
  }
  if (relu)
#pragma unroll
    for (int i = 0; i < 16; ++i) y[i] = fmaxf(y[i], 0.f);
  uint4 o0, o1;
#pragma unroll
  for (int i = 0; i < 4; ++i) {
    ((unsigned int*)&o0)[i] = (unsigned int)f2b(y[2 * i]) | ((unsigned int)f2b(y[2 * i + 1]) << 16);
    ((unsigned int*)&o1)[i] = (unsigned int)f2b(y[8 + 2 * i]) | ((unsigned int)f2b(y[8 + 2 * i + 1]) << 16);
  }
  *(uint4*)p = o0;
  *(uint4*)(p + 8) = o1;
}

// ---------------- cont path body (BN -> Linear(8->1024) -> LN -> ReLU) ----------
__device__ __forceinline__ void cont_body(const float* __restrict__ cx,
                                          const float* __restrict__ part_bn,
                                          const float* __restrict__ bn_g,
                                          const float* __restrict__ bn_b,
                                          const float* __restrict__ W,
                                          const float* __restrict__ cb,
                                          const float* __restrict__ g,
                                          const float* __restrict__ bb,
                                          u16* __restrict__ out,
                                          int row0, int tid) {
  __shared__ float sp[4][16];
  __shared__ float tt[16];
  __shared__ float ab[2][8];
  __shared__ float xn[8][8];
  __shared__ float rr1[4][8], rr2[4][8];

  if (tid < 64) {
    int f = tid & 15, qd = tid >> 4;
    float s = 0.f;
    for (int j = qd * 16; j < qd * 16 + 16; ++j) s += part_bn[j * 16 + f];
    sp[qd][f] = s;
  }
  __syncthreads();
  if (tid < 16) tt[tid] = sp[0][tid] + sp[1][tid] + sp[2][tid] + sp[3][tid];
  __syncthreads();
  if (tid < 8) {
    float mu = tt[tid] * (1.f / 16384.f);
    float var = tt[8 + tid] * (1.f / 16384.f) - mu * mu;
    float a = rsqrtf(var + EPS) * bn_g[tid];
    ab[0][tid] = a;
    ab[1][tid] = bn_b[tid] - mu * a;
  }
  __syncthreads();
  if (tid < 64) {
    int r = tid >> 3, f = tid & 7;
    xn[r][f] = ab[0][f] * cx[(row0 + r) * 8 + f] + ab[1][f];
  }
  __syncthreads();

  int c = tid * 4;
  float4 cbv = *(const float4*)(cb + c);
  float acc[8][4];
#pragma unroll
  for (int r = 0; r < 8; ++r) {
    acc[r][0] = cbv.x; acc[r][1] = cbv.y; acc[r][2] = cbv.z; acc[r][3] = cbv.w;
  }
  for (int k = 0; k < 8; ++k) {
    float4 w4 = *(const float4*)(W + k * 1024 + c);
#pragma unroll
    for (int r = 0; r < 8; ++r) {
      float xv = xn[r][k];
      acc[r][0] = fmaf(xv, w4.x, acc[r][0]);
      acc[r][1] = fmaf(xv, w4.y, acc[r][1]);
      acc[r][2] = fmaf(xv, w4.z, acc[r][2]);
      acc[r][3] = fmaf(xv, w4.w, acc[r][3]);
    }
  }
  float s1[8], s2[8];
#pragma unroll
  for (int r = 0; r < 8; ++r) {
    s1[r] = acc[r][0] + acc[r][1] + acc[r][2] + acc[r][3];
    s2[r] = acc[r][0] * acc[r][0] + acc[r][1] * acc[r][1] +
            acc[r][2] * acc[r][2] + acc[r][3] * acc[r][3];
  }
#pragma unroll
  for (int off = 32; off; off >>= 1)
#pragma unroll
    for (int r = 0; r < 8; ++r) {
      s1[r] += __shfl_down(s1[r], off);
      s2[r] += __shfl_down(s2[r], off);
    }
  int lane = tid & 63, wv = tid >> 6;
  if (lane == 0)
#pragma unroll
    for (int r = 0; r < 8; ++r) { rr1[wv][r] = s1[r]; rr2[wv][r] = s2[r]; }
  __syncthreads();
  float4 gv = *(const float4*)(g + c);
  float4 bv = *(const float4*)(bb + c);
#pragma unroll
  for (int r = 0; r < 8; ++r) {
    float ss = rr1[0][r] + rr1[1][r] + rr1[2][r] + rr1[3][r];
    float qq = rr2[0][r] + rr2[1][r] + rr2[2][r] + rr2[3][r];
    float mean = ss * (1.f / 1024.f);
    float var = qq * (1.f / 1024.f) - mean * mean;
    float rs = rsqrtf(var + EPS);
    float y0 = fmaxf((acc[r][0] - mean) * rs * gv.x + bv.x, 0.f);
    float y1 = fmaxf((acc[r][1] - mean) * rs * gv.y + bv.y, 0.f);
    float y2 = fmaxf((acc[r][2] - mean) * rs * gv.z + bv.z, 0.f);
    float y3 = fmaxf((acc[r][3] - mean) * rs * gv.w + bv.w, 0.f);
    ushort4 o; o.x = f2b(y0); o.y = f2b(y1); o.z = f2b(y2); o.w = f2b(y3);
    *(ushort4*)(out + (size_t)(row0 + r) * 1024 + c) = o;
  }
}

// ---------------- fused mid dispatch ---------------------------------------------
// grid: [0,4096) ln(X1) | [4096,4608) combWT | [4608,4672) wvog | [4672,6720) cont
//       | 6720 bc = bv.Wo[:,1023] + bo[1023]
__global__ __launch_bounds__(256) void mid_k(
    u16* __restrict__ X1, const float* __restrict__ cate_g,
    const float* __restrict__ cate_bb,
    const float* __restrict__ comb_W, u16* __restrict__ combWT,
    const float* __restrict__ Wv, const float* __restrict__ Wo,
    const float* __restrict__ comb_g, const float* __restrict__ comb_bbv,
    u16* __restrict__ wvob_hi, u16* __restrict__ wvob_lo,
    float* __restrict__ Swg, float* __restrict__ Swb,
    const float* __restrict__ bv, const float* __restrict__ bo,
    float* __restrict__ bc,
    const float* __restrict__ cx, const float* __restrict__ part_bn,
    const float* __restrict__ bn_g, const float* __restrict__ bn_b,
    const float* __restrict__ cont_W, const float* __restrict__ cont_b,
    const float* __restrict__ cont_g, const float* __restrict__ cont_bb,
    u16* __restrict__ X2) {
  __shared__ float shmem[64 * 65];
  const int bid = blockIdx.x, tid = threadIdx.x;
  if (bid < 4096) {                      // LN(X1) + ReLU
    ln_body(X1, cate_g, cate_bb, 1, bid, tid);
    return;
  }
  if (bid < 4608) {                      // combWT transpose fp32->bf16 (K=2048)
    int local = bid - 4096;
    int n0 = (local & 15) * 64, k0 = (local >> 4) * 64;
    int c = tid & 63, r0 = tid >> 6;
#pragma unroll
    for (int i = 0; i < 16; ++i) {
      int r = r0 + i * 4;
      shmem[r * 65 + c] = comb_W[(size_t)(k0 + r) * 1024 + n0 + c];
    }
    __syncthreads();
#pragma unroll
    for (int i = 0; i < 16; ++i) {
      int r = r0 + i * 4;
      combWT[(size_t)(n0 + r) * 2048 + k0 + c] = f2b(shmem[c * 65 + r]);
    }
    return;
  }
  if (bid < 4672) {                      // wvog (bf16 hi+lo), Swg/Swb
    int local = bid - 4608;
    int h = local >> 2, jc = local & 3;
    if (tid < 64) shmem[tid] = Wo[(size_t)(h * 64 + tid) * 1024 + 1023];
    __syncthreads();
    int j = jc * 256 + tid;
    const float* vr = Wv + (size_t)j * 1024 + h * 64;
    float s = 0.f;
    for (int d4 = 0; d4 < 64; d4 += 4) {
      float4 w4 = *(const float4*)(vr + d4);
      s = fmaf(w4.x, shmem[d4], s);
      s = fmaf(w4.y, shmem[d4 + 1], s);
      s = fmaf(w4.z, shmem[d4 + 2], s);
      s = fmaf(w4.w, shmem[d4 + 3], s);
    }
    float sg_ = s * comb_g[j];
    u16 hi = f2b(sg_);
    float lo = sg_ - b2f(hi);
    wvob_hi[h * 1024 + j] = hi;
    wvob_lo[h * 1024 + j] = f2b(lo);
    float swgp = sg_;
    float swbp = s * comb_bbv[j];
#pragma unroll
    for (int off = 32; off; off >>= 1) {
      swgp += __shfl_down(swgp, off);
      swbp += __shfl_down(swbp, off);
    }
    int lane = tid & 63, wv = tid >> 6;
    if (lane == 0) { shmem[64 + wv] = swgp; shmem[68 + wv] = swbp; }
    __syncthreads();
    if (tid == 0) {
      atomicAdd(&Swg[h], shmem[64] + shmem[65] + shmem[66] + shmem[67]);
      atomicAdd(&Swb[h], shmem[68] + shmem[69] + shmem[70] + shmem[71]);
    }
    return;
  }
  if (bid < 6720) {                      // cont path -> X2
    int row0 = (bid - 4672) * 8;
    cont_body(cx, part_bn, bn_g, bn_b, cont_W, cont_b, cont_g, cont_bb, X2,
              row0, tid);
    return;
  }
  {                                      // bc = bv . Wo[:,1023] + bo[1023]
    float s = 0.f;
    for (int i = tid; i < 1024; i += 256)
      s = fmaf(bv[i], Wo[(size_t)i * 1024 + 1023], s);
#pragma unroll
    for (int off = 32; off; off >>= 1) s += __shfl_down(s, off);
    int lane = tid & 63, wv = tid >> 6;
    if (lane == 0) shmem[wv] = s;
    __syncthreads();
    if (tid == 0) bc[0] = shmem[0] + shmem[1] + shmem[2] + shmem[3] + bo[1023];
  }
}

// ---------------- fused Q-projection + K-fold, grid 64 = (h, jc) ----------------
// Each block: stage+LN the 16 query rows, compute Q[:, h*64..h*64+63] fully
// in-block (k split over 4 thread groups, LDS reduce, bq folded), then run
// the kq quarter jc directly off LDS. Q is computed 4x redundantly across the
// jc blocks (bit-identical). Outputs: qtb (g-folded bf16), bkq, Sg, Sb.
__global__ __launch_bounds__(256) void qk_k(const u16* __restrict__ x,
                                            const float* __restrict__ g,
                                            const float* __restrict__ bb,
                                            const float* __restrict__ Wq,
                                            const float* __restrict__ bq,
                                            const float* __restrict__ Wk,
                                            const float* __restrict__ bk,
                                            u16* __restrict__ qtb,
                                            float* __restrict__ bkq,
                                            float* __restrict__ Sg,
                                            float* __restrict__ Sb) {
  __shared__ u16 xs[16][1024];
  __shared__ float part[4][16][64];
  __shared__ float ps1[16][16], ps2[16][16];
  __shared__ float sm[16], sr[16];
  __shared__ float Qs[16][64];
  __shared__ float rg[4][16], rb[4][16];
  int tid = threadIdx.x;
  int h = blockIdx.x >> 2, jc = blockIdx.x & 3;

  // stage raw rows (b, 1023)
  for (int i = tid; i < 4096; i += 256) {
    int b = i >> 8, off = (i & 255) * 4;
    *(ushort4*)&xs[b][off] =
        *(const ushort4*)(x + ((size_t)(b * 1024 + 1023)) * 1024 + off);
  }
  __syncthreads();
  // per-row LN stats: 16 threads/row, 64 cols each
  {
    int b = tid >> 4, seg = tid & 15;
    float s = 0.f, s2 = 0.f;
    for (int k = seg * 64; k < seg * 64 + 64; ++k) {
      float v = b2f(xs[b][k]);
      s += v;
      s2 = fmaf(v, v, s2);
    }
    ps1[b][seg] = s;
    ps2[b][seg] = s2;
  }
  __syncthreads();
  if (tid < 16) {
    float s = 0.f, s2 = 0.f;
#pragma unroll
    for (int j = 0; j < 16; ++j) { s += ps1[tid][j]; s2 += ps2[tid][j]; }
    float mean = s * (1.f / 1024.f);
    float var = s2 * (1.f / 1024.f) - mean * mean;
    sm[tid] = mean;
    sr[tid] = rsqrtf(var + EPS);
  }
  __syncthreads();
  // normalize in place
  for (int i = tid; i < 4096; i += 256) {
    int b = i >> 8, off = (i & 255) * 4;
    ushort4 u = *(ushort4*)&xs[b][off];
    float4 gv = *(const float4*)(g + off);
    float4 bvv = *(const float4*)(bb + off);
    float m = sm[b], r = sr[b];
    ushort4 o;
    o.x = f2b((b2f(u.x) - m) * r * gv.x + bvv.x);
    o.y = f2b((b2f(u.y) - m) * r * gv.y + bvv.y);
    o.z = f2b((b2f(u.z) - m) * r * gv.z + bvv.z);
    o.w = f2b((b2f(u.w) - m) * r * gv.w + bvv.w);
    *(ushort4*)&xs[b][off] = o;
  }
  __syncthreads();
  // Q[:, h*64+c] partials over k-quarter kq
  {
    int c = tid & 63;
    int kq = tid >> 6;
    int col = h * 64 + c;
    float acc[16];
#pragma unroll
    for (int b = 0; b < 16; ++b) acc[b] = 0.f;
    for (int k = kq * 256; k < kq * 256 + 256; ++k) {
      float wv = Wq[(size_t)k * 1024 + col];
#pragma unroll
      for (int b = 0; b < 16; ++b) acc[b] = fmaf(b2f(xs[b][k]), wv, acc[b]);
    }
#pragma unroll
    for (int b = 0; b < 16; ++b) part[kq][b][c] = acc[b];
  }
  __syncthreads();
  for (int i = tid; i < 1024; i += 256) {
    int b = i >> 6, d = i & 63;
    Qs[b][d] = part[0][b][d] + part[1][b][d] + part[2][b][d] + part[3][b][d] +
               bq[h * 64 + d];
  }
  __syncthreads();

  // kq part: j = jc*256 + tid
  int j = jc * 256 + tid;
  float acc[16];
#pragma unroll
  for (int b = 0; b < 16; ++b) acc[b] = 0.f;
  const float* wr = Wk + (size_t)j * 1024 + h * 64;
  for (int d4 = 0; d4 < 64; d4 += 4) {
    float4 w4 = *(const float4*)(wr + d4);
#pragma unroll
    for (int b = 0; b < 16; ++b) {
      acc[b] = fmaf(w4.x, Qs[b][d4], acc[b]);
      acc[b] = fmaf(w4.y, Qs[b][d4 + 1], acc[b]);
      acc[b] = fmaf(w4.z, Qs[b][d4 + 2], acc[b]);
      acc[b] = fmaf(w4.w, Qs[b][d4 + 3], acc[b]);
    }
  }
  float gj = g[j], bbj = bb[j];
  float sgp[16], sbp[16];
#pragma unroll
  for (int b = 0; b < 16; ++b) {
    u16 qg = f2b(acc[b] * gj);
    qtb[((size_t)b * 16 + h) * 1024 + j] = qg;
    sgp[b] = b2f(qg);            // match what the MFMA will see
    sbp[b] = acc[b] * bbj;
  }
#pragma unroll
  for (int off = 32; off; off >>= 1)
#pragma unroll
    for (int b = 0; b < 16; ++b) {
      sgp[b] += __shfl_down(sgp[b], off);
      sbp[b] += __shfl_down(sbp[b], off);
    }
  int lane = tid & 63, wv = tid >> 6;
  if (lane == 0)
#pragma unroll
    for (int b = 0; b < 16; ++b) { rg[wv][b] = sgp[b]; rb[wv][b] = sbp[b]; }
  __syncthreads();
  if (tid < 16) {
    int b = tid;
    atomicAdd(&Sg[b * 16 + h], rg[0][b] + rg[1][b] + rg[2][b] + rg[3][b]);
    atomicAdd(&Sb[b * 16 + h], rb[0][b] + rb[1][b] + rb[2][b] + rb[3][b]);
  }
  if (jc == 0 && tid < 16) {
    int b = tid;
    float s = 0.f;
    for (int d = 0; d < 64; ++d) s = fmaf(bk[h * 64 + d], Qs[b][d], s);
    bkq[b * 16 + h] = s;
  }
}

// ---------------- scores + y, grid 1024 = (b, 16-key group); k split over waves --
__global__ __launch_bounds__(256) void score_k(
    const u16* __restrict__ x, const u16* __restrict__ qtb,
    const float* __restrict__ bkq, const int* __restrict__ mask,
    const u16* __restrict__ whi, const u16* __restrict__ wlo,
    const float* __restrict__ Sg, const float* __restrict__ Sb,
    const float* __restrict__ Swg, const float* __restrict__ Swb,
    float* __restrict__ sc, float* __restrict__ y) {
  int b = blockIdx.x >> 6, kg = blockIdx.x & 63;
  int tid = threadIdx.x;
  int l = tid & 63, w = tid >> 6;     // w = k-quarter
  int keybase = kg * 16;
  int lr = l & 15, ls = l >> 4;
  int masked = (mask[b * 1024 + 1023] == 0);

  bf16x8 ones;
#pragma unroll
  for (int j = 0; j < 8; ++j) ones[j] = (short)0x3F80;  // bf16 1.0

  f32x4 acc = (f32x4){0.f, 0.f, 0.f, 0.f};
  f32x4 acy = (f32x4){0.f, 0.f, 0.f, 0.f};
  f32x4 as1 = (f32x4){0.f, 0.f, 0.f, 0.f};
  f32x4 as2 = (f32x4){0.f, 0.f, 0.f, 0.f};
  const u16* xb = x + (size_t)b * 1024 * 1024;
  const u16* qb = qtb + (size_t)b * 16 * 1024;
  const int k0beg = w * 256;
  for (int k0 = k0beg; k0 < k0beg + 256; k0 += 32) {
    bf16x8 bfr = *(const bf16x8*)&qb[(size_t)lr * 1024 + k0 + ls * 8];
    bf16x8 bh  = *(const bf16x8*)&whi[(size_t)lr * 1024 + k0 + ls * 8];
    bf16x8 bl  = *(const bf16x8*)&wlo[(size_t)lr * 1024 + k0 + ls * 8];
    bf16x8 afr = *(const bf16x8*)&xb[(size_t)(keybase + lr) * 1024 + k0 + ls * 8];
    acc = __builtin_amdgcn_mfma_f32_16x16x32_bf16(afr, bfr, acc, 0, 0, 0);
    acy = __builtin_amdgcn_mfma_f32_16x16x32_bf16(afr, bh, acy, 0, 0, 0);
    acy = __builtin_amdgcn_mfma_f32_16x16x32_bf16(afr, bl, acy, 0, 0, 0);
    as1 = __builtin_amdgcn_mfma_f32_16x16x32_bf16(afr, ones, as1, 0, 0, 0);
    as2 = __builtin_amdgcn_mfma_f32_16x16x32_bf16(afr, afr, as2, 0, 0, 0);
  }

  __shared__ float red[3][64][16];
  if (w > 0) {
    float* r = red[w - 1][l];
#pragma unroll
    for (int q = 0; q < 4; ++q) {
      r[q] = acc[q]; r[4 + q] = acy[q]; r[8 + q] = as1[q]; r[12 + q] = as2[q];
    }
  }
  __syncthreads();
  if (w == 0) {
#pragma unroll
    for (int i = 0; i < 3; ++i) {
      const float* r = red[i][l];
#pragma unroll
      for (int q = 0; q < 4; ++q) {
        acc[q] += r[q]; acy[q] += r[4 + q]; as1[q] += r[8 + q]; as2[q] += r[12 + q];
      }
    }
    int h = lr;
    float bq_  = bkq[b * 16 + h];
    float Sgv  = Sg[b * 16 + h];
    float Sbv  = Sb[b * 16 + h];
    float Swgv = Swg[h];
    float Swbv = Swb[h];
#pragma unroll
    for (int q = 0; q < 4; ++q) {
      int key = keybase + ls * 4 + q;
      float s1 = as1[q];
      float s2 = __shfl(as2[q], ls * 4 + q + 16 * ls);
      float mean = s1 * (1.f / 1024.f);
      float var  = s2 * (1.f / 1024.f) - mean * mean;
      float rs   = rsqrtf(var + EPS);
      float sraw = rs * acc[q] - rs * mean * Sgv + Sbv + bq_;
      float v = masked ? 0.f : sraw * 0.125f;
      sc[((size_t)b * 16 + h) * 1024 + key] = v;
      y[((size_t)b * 16 + h) * 1024 + key] =
          rs * acy[q] - rs * mean * Swgv + Swbv;
    }
  }
}

// ---------------- fin: softmax(sc[bh]) . y[bh] -> atomicAdd out[b] (+bc once) ----
__global__ __launch_bounds__(256) void fin_k(const float* __restrict__ sc,
                                             const float* __restrict__ y,
                                             const float* __restrict__ bc,
                                             float* __restrict__ out) {
  int bh = blockIdx.x, tid = threadIdx.x;
  float4 v = ((const float4*)(sc + (size_t)bh * 1024))[tid];
  float m = fmaxf(fmaxf(v.x, v.y), fmaxf(v.z, v.w));
#pragma unroll
  for (int off = 32; off; off >>= 1) m = fmaxf(m, __shfl_down(m, off));
  __shared__ float rm[4], rs_[4], rd_[4];
  int lane = tid & 63, wv = tid >> 6;
  if (lane == 0) rm[wv] = m;
  __syncthreads();
  m = fmaxf(fmaxf(rm[0], rm[1]), fmaxf(rm[2], rm[3]));
  float e0 = expf(v.x - m), e1 = expf(v.y - m), e2 = expf(v.z - m), e3 = expf(v.w - m);
  float4 yv = ((const float4*)(y + (size_t)bh * 1024))[tid];
  float s = e0 + e1 + e2 + e3;
  float d = e0 * yv.x + e1 * yv.y + e2 * yv.z + e3 * yv.w;
#pragma unroll
  for (int off = 32; off; off >>= 1) {
    s += __shfl_down(s, off);
    d += __shfl_down(d, off);
  }
  if (lane == 0) { rs_[wv] = s; rd_[wv] = d; }
  __syncthreads();
  if (tid == 0) {
    float Z = rs_[0] + rs_[1] + rs_[2] + rs_[3];
    float D = rd_[0] + rd_[1] + rd_[2] + rd_[3];
    float add = D / Z;
    if ((bh & 15) == 0) add += bc[0];
    atomicAdd(&out[bh >> 4], add);
  }
}

extern "C" void kernel_launch(void* const* d_in, const int* in_sizes, int n_in,
                              void* d_out, int out_size, void* d_ws, size_t ws_size,
                              hipStream_t stream) {
  const int*   cate_x  = (const int*)d_in[0];
  const float* cont_x  = (const float*)d_in[1];
  const int*   mask    = (const int*)d_in[2];
  const float* emb     = (const float*)d_in[3];
  const float* cate_W  = (const float*)d_in[4];
  const float* cate_b  = (const float*)d_in[5];
  const float* cate_g  = (const float*)d_in[6];
  const float* cate_bb = (const float*)d_in[7];
  const float* bn_g    = (const float*)d_in[8];
  const float* bn_b    = (const float*)d_in[9];
  const float* cont_W  = (const float*)d_in[10];
  const float* cont_b  = (const float*)d_in[11];
  const float* cont_g  = (const float*)d_in[12];
  const float* cont_bb = (const float*)d_in[13];
  const float* Wq = (const float*)d_in[18]; const float* bq = (const float*)d_in[19];
  const float* Wk = (const float*)d_in[20]; const float* bk = (const float*)d_in[21];
  const float* Wv = (const float*)d_in[22]; const float* bv = (const float*)d_in[23];
  const float* Wo = (const float*)d_in[24]; const float* bo = (const float*)d_in[25];
  const float* comb_W  = (const float*)d_in[14];
  const float* comb_b  = (const float*)d_in[15];
  const float* comb_g  = (const float*)d_in[16];
  const float* comb_bb = (const float*)d_in[17];
  float* out = (float*)d_out;

  char* w = (char*)d_ws;
  float* part_bn = (float*)(w + 256);         // 64*16 f32 = 4KB
  u16* embb      = (u16*)(w + 131328);        // 1.25MB
  u16* cateWT    = (u16*)(w + 1411328);       // 1MB
  u16* combWT    = (u16*)(w + 2459904);       // 4MB
  float* sc      = (float*)(w + 6654208);     // 1MB scores
  u16*   qtb     = (u16*)(w + 7702784);       // 512KB
  float* bkq     = (float*)(w + 8292608);     // 1KB
  float* ybuf    = (float*)(w + 8388608);     // 1MB y
  u16* wvob_hi   = (u16*)(w + 9437184);       // 32KB
  u16* wvob_lo   = (u16*)(w + 9469952);       // 32KB
  float* Sall    = (float*)(w + 10162176);    // Sg[256]|Sb[256]|Swg[16]|Swb[16]|bc
  float* Sg      = Sall;
  float* Sb      = Sall + 256;
  float* Swg     = Sall + 512;
  float* Swb     = Sall + 528;
  float* bc      = Sall + 552;                // 1 f32 (written by mid_k)
  u16* X1        = (u16*)(w + 10848512);      // 32MB
  u16* X2        = X1 + (size_t)16777216;     // 32MB
  u16* xb        = X2 + (size_t)16777216;     // 32MB (RAW gemm2 output, pre-LN)

  // preprocessing (zero out+Sall | BN partials | embconv | cateWT)
  prep_k<<<818, 256, 0, stream>>>(cont_x, part_bn, out, Sall, emb, embb,
                                  cate_W, cateWT);

  // cate: gathered-emb GEMM (K=512) -> X1
  gemm256<1><<<256, 512, 0, stream>>>(nullptr, nullptr, cate_x, embb, cateWT,
                                      cate_b, X1, 512);
  // fused: LN+ReLU(X1) | combWT | wvog hi/lo + Swg/Swb | cont -> X2 | bc
  mid_k<<<6721, 256, 0, stream>>>(X1, cate_g, cate_bb, comb_W, combWT, Wv, Wo,
                                  comb_g, comb_bb, wvob_hi, wvob_lo, Swg, Swb,
                                  bv, bo, bc, cont_x, part_bn, bn_g, bn_b,
                                  cont_W, cont_b, cont_g, cont_bb, X2);
  // combine: concat GEMM (K=2048) -> xb RAW (pre-LN)
  gemm256<2><<<256, 512, 0, stream>>>(X1, X2, nullptr, nullptr, combWT,
                                      comb_b, xb, 2048);

  // folded attention path (LN applied algebraically; stats computed in-kernel)
  qk_k<<<64, 256, 0, stream>>>(xb, comb_g, comb_bb, Wq, bq, Wk, bk, qtb, bkq,
                               Sg, Sb);
  score_k<<<1024, 256, 0, stream>>>(xb, qtb, bkq, mask, wvob_hi, wvob_lo,
                                    Sg, Sb, Swg, Swb, sc, ybuf);
  fin_k<<<256, 256, 0, stream>>>(sc, ybuf, bc, out);
}

// Round 11
// 181.301 us; speedup vs baseline: 1.1488x; 1.1488x over previous
//
#include <hip/hip_runtime.h>
#include <hip/hip_bf16.h>
#include <math.h>

// B=16, S=1024, CC=8, CF=8, E=64, H=1024, NH=16, DH=64, VOCAB=10000
// Output = out[:, -1:, -1] -> 16 f32
// Attention algebra: only query S-1 is needed. y[b,h,k]=x'_k.wvo_h folded into
// score; final LN(xb) folded algebraically (stats via MFMA in score_k, inline
// in qproj_k). EXACT REVERT to the round-8 state (181.7us, best verified):
// round-9 pre-gather (+4us) and round-10 qk_k fusion (+27us, 64-block
// low-occupancy double-serial) both refuted. Lesson: dispatch boundary costs
// only ~3-5us here; never pay for one with occupancy or redundant work.
// GEMMs frozen at round-3 form (72.0us, VGPR 116; round-5 regalloc lesson).
#define EPS 1e-5f

typedef unsigned short u16;
typedef __attribute__((ext_vector_type(8))) short bf16x8;
typedef __attribute__((ext_vector_type(4))) float f32x4;

__device__ __forceinline__ float b2f(u16 u) {
  union { unsigned int i; float f; } v; v.i = ((unsigned int)u) << 16; return v.f;
}
__device__ __forceinline__ u16 f2b(float f) {
  union { float f; unsigned int i; } v; v.f = f;
  unsigned int r = v.i + 0x7fff + ((v.i >> 16) & 1);
  return (u16)(r >> 16);
}

__device__ __forceinline__ void gload_lds16(const u16* g, u16* l) {
  __builtin_amdgcn_global_load_lds(
      (const __attribute__((address_space(1))) unsigned int*)g,
      (__attribute__((address_space(3))) unsigned int*)l, 16, 0, 0);
}

// ---------------- preprocessing needed BEFORE gemm1 -----------------------------
__global__ __launch_bounds__(256) void prep_k(
    const float* __restrict__ cx, float* __restrict__ part_bn,
    float* __restrict__ out, float* __restrict__ Sall,
    const float* __restrict__ emb, u16* __restrict__ embb,
    const float* __restrict__ cate_W, u16* __restrict__ cateWT) {
  __shared__ float shmem[64 * 65];
  const int bid = blockIdx.x, tid = threadIdx.x;

  if (bid == 0) {
    if (tid < 16) out[tid] = 0.f;                        // d_out accumulator
    for (int i = tid; i < 544; i += 256) Sall[i] = 0.f;  // Sg|Sb|Swg|Swb
    return;
  }
  if (bid <= 64) {                       // BN partial sums
    int pb = bid - 1;
    int gid = pb * 256 + tid;
    float4 a = ((const float4*)cx)[2 * gid];
    float4 b = ((const float4*)cx)[2 * gid + 1];
    float v[16];
    v[0] = a.x; v[1] = a.y; v[2] = a.z; v[3] = a.w;
    v[4] = b.x; v[5] = b.y; v[6] = b.z; v[7] = b.w;
#pragma unroll
    for (int i = 0; i < 8; ++i) v[8 + i] = v[i] * v[i];
#pragma unroll
    for (int off = 32; off; off >>= 1)
#pragma unroll
      for (int i = 0; i < 16; ++i) v[i] += __shfl_down(v[i], off);
    int l = tid & 63, wv_ = tid >> 6;
    if (l == 0)
#pragma unroll
      for (int i = 0; i < 16; ++i) shmem[wv_ * 16 + i] = v[i];
    __syncthreads();
    if (tid < 16)
      part_bn[pb * 16 + tid] = shmem[tid] + shmem[16 + tid] + shmem[32 + tid] + shmem[48 + tid];
    return;
  }
  if (bid <= 689) {                      // embconv
    int i = (bid - 65) * 256 + tid;
    if (i < 160000) {
      float4 v = ((const float4*)emb)[i];
      ushort4 u; u.x = f2b(v.x); u.y = f2b(v.y); u.z = f2b(v.z); u.w = f2b(v.w);
      ((ushort4*)embb)[i] = u;
    }
    return;
  }
  {                                      // cateWT transpose fp32->bf16 (K=512)
    int local = bid - 690;
    int n0 = (local & 15) * 64, k0 = (local >> 4) * 64;
    int c = tid & 63, r0 = tid >> 6;
#pragma unroll
    for (int i = 0; i < 16; ++i) {
      int r = r0 + i * 4;
      shmem[r * 65 + c] = cate_W[(size_t)(k0 + r) * 1024 + n0 + c];
    }
    __syncthreads();
#pragma unroll
    for (int i = 0; i < 16; ++i) {
      int r = r0 + i * 4;
      cateWT[(size_t)(n0 + r) * 512 + k0 + c] = f2b(shmem[c * 65 + r]);
    }
  }
}

// ---------------- 256x256 MFMA GEMM, 8 waves, BK=64, 8-phase schedule -----------
// FROZEN round-3 kernel (72.0us, VGPR 116): XCD-chunked swizzle, 8-phase
// counted-vmcnt, MODE-1 sidx stash. No epilogue additions (round-5 lesson).
template <int MODE>
__global__ __launch_bounds__(512) void gemm256(
    const u16* __restrict__ A0, const u16* __restrict__ A1,
    const int* __restrict__ idx, const u16* __restrict__ embb,
    const u16* __restrict__ BT, const float* __restrict__ bias,
    u16* __restrict__ C, int K) {
  __shared__ u16 As[2][2][8192];
  __shared__ u16 Bs[2][2][8192];
  __shared__ int sidx[MODE == 1 ? 2048 : 4];
  const int tid = threadIdx.x;
  const int bid = blockIdx.x;
  const int chunk = gridDim.x >> 3;               // 32
  const int swz = (bid & 7) * chunk + (bid >> 3); // XCD-chunked, bijective
  const int row0 = (swz >> 2) * 256;
  const int col0 = (swz & 3) * 256;

  const int rr8 = tid >> 3;
  const int p8  = tid & 7;
  const int sl  = p8 ^ (rr8 & 7);

  const int l   = tid & 63;
  const int w   = tid >> 6;
  const int wrh = w >> 2;
  const int wcq = w & 3;
  const int hb  = wcq >> 1;
  const int rbb = (wcq & 1) * 64;
  const int lr  = l & 15;
  const int lk  = l >> 4;

  f32x4 acc[8][4];
#pragma unroll
  for (int m = 0; m < 8; ++m)
#pragma unroll
    for (int n = 0; n < 4; ++n) acc[m][n] = (f32x4){0.f, 0.f, 0.f, 0.f};

  const int nt = K >> 6;        // 8 (cate) or 32 (comb) -- always even
  const int nit = nt >> 1;

  if (MODE == 1) {              // stash all 256 rows x 8 k-chunk indices in LDS
    *(int4*)&sidx[tid * 4] = *(const int4*)&idx[row0 * 8 + tid * 4];
    __syncthreads();
  }

  auto stageA = [&](int t, int h) {               // one A half-tile: 2 loads
    const int k0 = t << 6;
    const int buf = t & 1;
#pragma unroll
    for (int i = 0; i < 2; ++i) {
      const u16* asrc;
      if (MODE == 1) {
        int id = sidx[(h * 128 + i * 64 + rr8) * 8 + (k0 >> 6)];
        asrc = embb + (size_t)id * 64 + sl * 8;
      } else {
        int ar = row0 + h * 128 + i * 64 + rr8;
        const u16* base = (k0 < 1024) ? A0 : A1;
        asrc = base + (size_t)ar * 1024 + (k0 & 1023) + sl * 8;
      }
      gload_lds16(asrc, &As[buf][h][i * 4096 + tid * 8]);
    }
  };
  auto stageB = [&](int t, int h) {               // one B half-tile: 2 loads
    const int k0 = t << 6;
    const int buf = t & 1;
#pragma unroll
    for (int i = 0; i < 2; ++i) {
      int br = col0 + h * 128 + i * 64 + rr8;
      gload_lds16(BT + (size_t)br * K + k0 + sl * 8,
                  &Bs[buf][h][i * 4096 + tid * 8]);
    }
  };

  bf16x8 bfr[4][2];
  auto loadB = [&](int buf) {                     // 8 ds_read_b128
#pragma unroll
    for (int n = 0; n < 4; ++n)
#pragma unroll
      for (int ks = 0; ks < 2; ++ks) {
        int rowb = rbb + n * 16 + lr;
        int ph = (ks * 4 + lk) ^ (lr & 7);
        bfr[n][ks] = *(const bf16x8*)&Bs[buf][hb][rowb * 64 + ph * 8];
      }
  };
  auto loadA = [&](bf16x8 (&af)[2][2], int buf, int q) {  // 4 ds_read_b128
#pragma unroll
    for (int mm = 0; mm < 2; ++mm)
#pragma unroll
      for (int ks = 0; ks < 2; ++ks) {
        int rowa = (q * 2 + mm) * 16 + lr;
        int ph = (ks * 4 + lk) ^ (lr & 7);
        af[mm][ks] = *(const bf16x8*)&As[buf][wrh][rowa * 64 + ph * 8];
      }
  };
  auto mfma_quad = [&](bf16x8 (&af)[2][2], int q) {       // 16 MFMA
    __builtin_amdgcn_s_setprio(1);
#pragma unroll
    for (int ks = 0; ks < 2; ++ks)
#pragma unroll
      for (int mm = 0; mm < 2; ++mm)
#pragma unroll
        for (int n = 0; n < 4; ++n)
          acc[q * 2 + mm][n] = __builtin_amdgcn_mfma_f32_16x16x32_bf16(
              af[mm][ks], bfr[n][ks], acc[q * 2 + mm][n], 0, 0, 0);
    __builtin_amdgcn_s_setprio(0);
  };

  // ---- prologue: tile0 A+B, tile1 B; wait tile0 (leave tile1-B in flight)
  stageA(0, 0); stageA(0, 1);
  stageB(0, 0); stageB(0, 1);
  stageB(1, 0); stageB(1, 1);
  asm volatile("s_waitcnt vmcnt(4)" ::: "memory");
  __builtin_amdgcn_s_barrier();

  for (int it = 0; it < nit; ++it) {
    const int T = it * 2;
    const bool more = (T + 2 < nt);     // also == (T+3 < nt) since nt even
    bf16x8 af[2][2];

    // -------- tile T (buf 0) --------
    loadB(0); loadA(af, 0, 0);
    stageA(T + 1, 0);
    __builtin_amdgcn_s_barrier();
    asm volatile("s_waitcnt lgkmcnt(0)" ::: "memory");
    mfma_quad(af, 0);
    __builtin_amdgcn_s_barrier();
    loadA(af, 0, 1);
    stageA(T + 1, 1);
    __builtin_amdgcn_s_barrier();
    asm volatile("s_waitcnt lgkmcnt(0)" ::: "memory");
    mfma_quad(af, 1);
    __builtin_amdgcn_s_barrier();
    loadA(af, 0, 2);
    if (more) stageB(T + 2, 0);
    __builtin_amdgcn_s_barrier();
    asm volatile("s_waitcnt lgkmcnt(0)" ::: "memory");
    mfma_quad(af, 2);
    __builtin_amdgcn_s_barrier();
    loadA(af, 0, 3);
    if (more) stageB(T + 2, 1);
    __builtin_amdgcn_s_barrier();
    asm volatile("s_waitcnt lgkmcnt(0)" ::: "memory");
    mfma_quad(af, 3);
    if (more) asm volatile("s_waitcnt vmcnt(4)" ::: "memory");
    else      asm volatile("s_waitcnt vmcnt(0)" ::: "memory");
    __builtin_amdgcn_s_barrier();

    // -------- tile T+1 (buf 1) --------
    loadB(1); loadA(af, 1, 0);
    if (more) stageA(T + 2, 0);
    __builtin_amdgcn_s_barrier();
    asm volatile("s_waitcnt lgkmcnt(0)" ::: "memory");
    mfma_quad(af, 0);
    __builtin_amdgcn_s_barrier();
    loadA(af, 1, 1);
    if (more) stageA(T + 2, 1);
    __builtin_amdgcn_s_barrier();
    asm volatile("s_waitcnt lgkmcnt(0)" ::: "memory");
    mfma_quad(af, 1);
    __builtin_amdgcn_s_barrier();
    loadA(af, 1, 2);
    if (more) stageB(T + 3, 0);
    __builtin_amdgcn_s_barrier();
    asm volatile("s_waitcnt lgkmcnt(0)" ::: "memory");
    mfma_quad(af, 2);
    __builtin_amdgcn_s_barrier();
    loadA(af, 1, 3);
    if (more) stageB(T + 3, 1);
    __builtin_amdgcn_s_barrier();
    asm volatile("s_waitcnt lgkmcnt(0)" ::: "memory");
    mfma_quad(af, 3);
    if (it + 1 < nit) {
      asm volatile("s_waitcnt vmcnt(4)" ::: "memory");
      __builtin_amdgcn_s_barrier();
    }
  }

  float bv_[4];
#pragma unroll
  for (int n = 0; n < 4; ++n) bv_[n] = bias[col0 + wcq * 64 + n * 16 + lr];
#pragma unroll
  for (int m = 0; m < 8; ++m) {
#pragma unroll
    for (int n = 0; n < 4; ++n) {
      int cc = col0 + wcq * 64 + n * 16 + lr;
#pragma unroll
      for (int q4 = 0; q4 < 4; ++q4) {
        int rr = row0 + wrh * 128 + m * 16 + lk * 4 + q4;
        C[(size_t)rr * 1024 + cc] = f2b(acc[m][n][q4] + bv_[n]);
      }
    }
  }
}

// ---------------- In-place LayerNorm body (used by mid_k for X1) ----------------
__device__ __forceinline__ void ln_body(u16* __restrict__ buf,
                                        const float* __restrict__ g,
                                        const float* __restrict__ b, int relu,
                                        int blk, int tid) {
  int lane = tid & 63, wave = tid >> 6;
  size_t row = (size_t)blk * 4 + wave;
  u16* p = buf + row * 1024 + lane * 16;
  uint4 u0 = *(uint4*)p;
  uint4 u1 = *(uint4*)(p + 8);
  float x[16];
#pragma unroll
  for (int i = 0; i < 4; ++i) {
    unsigned int w0 = ((unsigned int*)&u0)[i];
    unsigned int w1 = ((unsigned int*)&u1)[i];
    x[2 * i]     = b2f((u16)(w0 & 0xffff));
    x[2 * i + 1] = b2f((u16)(w0 >> 16));
    x[8 + 2 * i]     = b2f((u16)(w1 & 0xffff));
    x[8 + 2 * i + 1] = b2f((u16)(w1 >> 16));
  }
  float s = 0.f, s2 = 0.f;
#pragma unroll
  for (int i = 0; i < 16; ++i) { s += x[i]; s2 += x[i] * x[i]; }
#pragma unroll
  for (int off = 32; off; off >>= 1) { s += __shfl_xor(s, off); s2 += __shfl_xor(s2, off); }
  float mean = s * (1.f / 1024.f);
  float var = s2 * (1.f / 1024.f) - mean * mean;
  float rs = rsqrtf(var + EPS);
  float y[16];
#pragma unroll
  for (int q = 0; q < 4; ++q) {
    float4 gv = *(const float4*)(g + lane * 16 + q * 4);
    float4 bv = *(const float4*)(b + lane * 16 + q * 4);
    y[4 * q]     = (x[4 * q]     - mean) * rs * gv.x + bv.x;
    y[4 * q + 1] = (x[4 * q + 1] - mean) * rs * gv.y + bv.y;
    y[4 * q + 2] = (x[4 * q + 2] - mean) * rs * gv.z + bv.z;
    y[4 * q + 3] = (x[4 * q + 3] - mean) * rs * gv.w + bv.w;
  }
  if (relu)
#pragma unroll
    for (int i = 0; i < 16; ++i) y[i] = fmaxf(y[i], 0.f);
  uint4 o0, o1;
#pragma unroll
  for (int i = 0; i < 4; ++i) {
    ((unsigned int*)&o0)[i] = (unsigned int)f2b(y[2 * i]) | ((unsigned int)f2b(y[2 * i + 1]) << 16);
    ((unsigned int*)&o1)[i] = (unsigned int)f2b(y[8 + 2 * i]) | ((unsigned int)f2b(y[8 + 2 * i + 1]) << 16);
  }
  *(uint4*)p = o0;
  *(uint4*)(p + 8) = o1;
}

// ---------------- cont path body (BN -> Linear(8->1024) -> LN -> ReLU) ----------
__device__ __forceinline__ void cont_body(const float* __restrict__ cx,
                                          const float* __restrict__ part_bn,
                                          const float* __restrict__ bn_g,
                                          const float* __restrict__ bn_b,
                                          const float* __restrict__ W,
                                          const float* __restrict__ cb,
                                          const float* __restrict__ g,
                                          const float* __restrict__ bb,
                                          u16* __restrict__ out,
                                          int row0, int tid) {
  __shared__ float sp[4][16];
  __shared__ float tt[16];
  __shared__ float ab[2][8];
  __shared__ float xn[8][8];
  __shared__ float rr1[4][8], rr2[4][8];

  if (tid < 64) {
    int f = tid & 15, qd = tid >> 4;
    float s = 0.f;
    for (int j = qd * 16; j < qd * 16 + 16; ++j) s += part_bn[j * 16 + f];
    sp[qd][f] = s;
  }
  __syncthreads();
  if (tid < 16) tt[tid] = sp[0][tid] + sp[1][tid] + sp[2][tid] + sp[3][tid];
  __syncthreads();
  if (tid < 8) {
    float mu = tt[tid] * (1.f / 16384.f);
    float var = tt[8 + tid] * (1.f / 16384.f) - mu * mu;
    float a = rsqrtf(var + EPS) * bn_g[tid];
    ab[0][tid] = a;
    ab[1][tid] = bn_b[tid] - mu * a;
  }
  __syncthreads();
  if (tid < 64) {
    int r = tid >> 3, f = tid & 7;
    xn[r][f] = ab[0][f] * cx[(row0 + r) * 8 + f] + ab[1][f];
  }
  __syncthreads();

  int c = tid * 4;
  float4 cbv = *(const float4*)(cb + c);
  float acc[8][4];
#pragma unroll
  for (int r = 0; r < 8; ++r) {
    acc[r][0] = cbv.x; acc[r][1] = cbv.y; acc[r][2] = cbv.z; acc[r][3] = cbv.w;
  }
  for (int k = 0; k < 8; ++k) {
    float4 w4 = *(const float4*)(W + k * 1024 + c);
#pragma unroll
    for (int r = 0; r < 8; ++r) {
      float xv = xn[r][k];
      acc[r][0] = fmaf(xv, w4.x, acc[r][0]);
      acc[r][1] = fmaf(xv, w4.y, acc[r][1]);
      acc[r][2] = fmaf(xv, w4.z, acc[r][2]);
      acc[r][3] = fmaf(xv, w4.w, acc[r][3]);
    }
  }
  float s1[8], s2[8];
#pragma unroll
  for (int r = 0; r < 8; ++r) {
    s1[r] = acc[r][0] + acc[r][1] + acc[r][2] + acc[r][3];
    s2[r] = acc[r][0] * acc[r][0] + acc[r][1] * acc[r][1] +
            acc[r][2] * acc[r][2] + acc[r][3] * acc[r][3];
  }
#pragma unroll
  for (int off = 32; off; off >>= 1)
#pragma unroll
    for (int r = 0; r < 8; ++r) {
      s1[r] += __shfl_down(s1[r], off);
      s2[r] += __shfl_down(s2[r], off);
    }
  int lane = tid & 63, wv = tid >> 6;
  if (lane == 0)
#pragma unroll
    for (int r = 0; r < 8; ++r) { rr1[wv][r] = s1[r]; rr2[wv][r] = s2[r]; }
  __syncthreads();
  float4 gv = *(const float4*)(g + c);
  float4 bv = *(const float4*)(bb + c);
#pragma unroll
  for (int r = 0; r < 8; ++r) {
    float ss = rr1[0][r] + rr1[1][r] + rr1[2][r] + rr1[3][r];
    float qq = rr2[0][r] + rr2[1][r] + rr2[2][r] + rr2[3][r];
    float mean = ss * (1.f / 1024.f);
    float var = qq * (1.f / 1024.f) - mean * mean;
    float rs = rsqrtf(var + EPS);
    float y0 = fmaxf((acc[r][0] - mean) * rs * gv.x + bv.x, 0.f);
    float y1 = fmaxf((acc[r][1] - mean) * rs * gv.y + bv.y, 0.f);
    float y2 = fmaxf((acc[r][2] - mean) * rs * gv.z + bv.z, 0.f);
    float y3 = fmaxf((acc[r][3] - mean) * rs * gv.w + bv.w, 0.f);
    ushort4 o; o.x = f2b(y0); o.y = f2b(y1); o.z = f2b(y2); o.w = f2b(y3);
    *(ushort4*)(out + (size_t)(row0 + r) * 1024 + c) = o;
  }
}

// ---------------- fused mid dispatch ---------------------------------------------
// grid: [0,4096) ln(X1) | [4096,4608) combWT | [4608,4672) wvog | [4672,6720) cont
//       | 6720 bc = bv.Wo[:,1023] + bo[1023]
__global__ __launch_bounds__(256) void mid_k(
    u16* __restrict__ X1, const float* __restrict__ cate_g,
    const float* __restrict__ cate_bb,
    const float* __restrict__ comb_W, u16* __restrict__ combWT,
    const float* __restrict__ Wv, const float* __restrict__ Wo,
    const float* __restrict__ comb_g, const float* __restrict__ comb_bbv,
    u16* __restrict__ wvob_hi, u16* __restrict__ wvob_lo,
    float* __restrict__ Swg, float* __restrict__ Swb,
    const float* __restrict__ bv, const float* __restrict__ bo,
    float* __restrict__ bc,
    const float* __restrict__ cx, const float* __restrict__ part_bn,
    const float* __restrict__ bn_g, const float* __restrict__ bn_b,
    const float* __restrict__ cont_W, const float* __restrict__ cont_b,
    const float* __restrict__ cont_g, const float* __restrict__ cont_bb,
    u16* __restrict__ X2) {
  __shared__ float shmem[64 * 65];
  const int bid = blockIdx.x, tid = threadIdx.x;
  if (bid < 4096) {                      // LN(X1) + ReLU
    ln_body(X1, cate_g, cate_bb, 1, bid, tid);
    return;
  }
  if (bid < 4608) {                      // combWT transpose fp32->bf16 (K=2048)
    int local = bid - 4096;
    int n0 = (local & 15) * 64, k0 = (local >> 4) * 64;
    int c = tid & 63, r0 = tid >> 6;
#pragma unroll
    for (int i = 0; i < 16; ++i) {
      int r = r0 + i * 4;
      shmem[r * 65 + c] = comb_W[(size_t)(k0 + r) * 1024 + n0 + c];
    }
    __syncthreads();
#pragma unroll
    for (int i = 0; i < 16; ++i) {
      int r = r0 + i * 4;
      combWT[(size_t)(n0 + r) * 2048 + k0 + c] = f2b(shmem[c * 65 + r]);
    }
    return;
  }
  if (bid < 4672) {                      // wvog (bf16 hi+lo), Swg/Swb
    int local = bid - 4608;
    int h = local >> 2, jc = local & 3;
    if (tid < 64) shmem[tid] = Wo[(size_t)(h * 64 + tid) * 1024 + 1023];
    __syncthreads();
    int j = jc * 256 + tid;
    const float* vr = Wv + (size_t)j * 1024 + h * 64;
    float s = 0.f;
    for (int d4 = 0; d4 < 64; d4 += 4) {
      float4 w4 = *(const float4*)(vr + d4);
      s = fmaf(w4.x, shmem[d4], s);
      s = fmaf(w4.y, shmem[d4 + 1], s);
      s = fmaf(w4.z, shmem[d4 + 2], s);
      s = fmaf(w4.w, shmem[d4 + 3], s);
    }
    float sg_ = s * comb_g[j];
    u16 hi = f2b(sg_);
    float lo = sg_ - b2f(hi);
    wvob_hi[h * 1024 + j] = hi;
    wvob_lo[h * 1024 + j] = f2b(lo);
    float swgp = sg_;
    float swbp = s * comb_bbv[j];
#pragma unroll
    for (int off = 32; off; off >>= 1) {
      swgp += __shfl_down(swgp, off);
      swbp += __shfl_down(swbp, off);
    }
    int lane = tid & 63, wv = tid >> 6;
    if (lane == 0) { shmem[64 + wv] = swgp; shmem[68 + wv] = swbp; }
    __syncthreads();
    if (tid == 0) {
      atomicAdd(&Swg[h], shmem[64] + shmem[65] + shmem[66] + shmem[67]);
      atomicAdd(&Swb[h], shmem[68] + shmem[69] + shmem[70] + shmem[71]);
    }
    return;
  }
  if (bid < 6720) {                      // cont path -> X2
    int row0 = (bid - 4672) * 8;
    cont_body(cx, part_bn, bn_g, bn_b, cont_W, cont_b, cont_g, cont_bb, X2,
              row0, tid);
    return;
  }
  {                                      // bc = bv . Wo[:,1023] + bo[1023]
    float s = 0.f;
    for (int i = tid; i < 1024; i += 256)
      s = fmaf(bv[i], Wo[(size_t)i * 1024 + 1023], s);
#pragma unroll
    for (int off = 32; off; off >>= 1) s += __shfl_down(s, off);
    int lane = tid & 63, wv = tid >> 6;
    if (lane == 0) shmem[wv] = s;
    __syncthreads();
    if (tid == 0) bc[0] = shmem[0] + shmem[1] + shmem[2] + shmem[3] + bo[1023];
  }
}

// ---------------- Q projection partials, grid 256 = (colblk 0..63, kq4 0..3) ----
// Each block: stage+LN its 16 rows (stats recomputed redundantly, L2-hot),
// compute partial Q over its 256-k quarter, write qpart[kq4]. bq folded into
// partial 0. kq_k sums the 4 partials.
__global__ __launch_bounds__(256) void qproj_k(const u16* __restrict__ x,
                                               const float* __restrict__ g,
                                               const float* __restrict__ bb,
                                               const float* __restrict__ Wq,
                                               const float* __restrict__ bq,
                                               float* __restrict__ qpart) {
  __shared__ u16 xs[16][1024];
  __shared__ float part[16][16][16];
  __shared__ float ps1[16][16], ps2[16][16];
  __shared__ float sm[16], sr[16];
  int tid = threadIdx.x;
  int cb = blockIdx.x >> 2, kq4 = blockIdx.x & 3;
  // stage raw rows (b, 1023)
  for (int i = tid; i < 4096; i += 256) {
    int b = i >> 8, off = (i & 255) * 4;
    *(ushort4*)&xs[b][off] =
        *(const ushort4*)(x + ((size_t)(b * 1024 + 1023)) * 1024 + off);
  }
  __syncthreads();
  // per-row LN stats: 16 threads/row, 64 cols each
  {
    int b = tid >> 4, seg = tid & 15;
    float s = 0.f, s2 = 0.f;
    for (int k = seg * 64; k < seg * 64 + 64; ++k) {
      float v = b2f(xs[b][k]);
      s += v;
      s2 = fmaf(v, v, s2);
    }
    ps1[b][seg] = s;
    ps2[b][seg] = s2;
  }
  __syncthreads();
  if (tid < 16) {
    float s = 0.f, s2 = 0.f;
#pragma unroll
    for (int j = 0; j < 16; ++j) { s += ps1[tid][j]; s2 += ps2[tid][j]; }
    float mean = s * (1.f / 1024.f);
    float var = s2 * (1.f / 1024.f) - mean * mean;
    sm[tid] = mean;
    sr[tid] = rsqrtf(var + EPS);
  }
  __syncthreads();
  // normalize in place
  for (int i = tid; i < 4096; i += 256) {
    int b = i >> 8, off = (i & 255) * 4;
    ushort4 u = *(ushort4*)&xs[b][off];
    float4 gv = *(const float4*)(g + off);
    float4 bvv = *(const float4*)(bb + off);
    float m = sm[b], r = sr[b];
    ushort4 o;
    o.x = f2b((b2f(u.x) - m) * r * gv.x + bvv.x);
    o.y = f2b((b2f(u.y) - m) * r * gv.y + bvv.y);
    o.z = f2b((b2f(u.z) - m) * r * gv.z + bvv.z);
    o.w = f2b((b2f(u.w) - m) * r * gv.w + bvv.w);
    *(ushort4*)&xs[b][off] = o;
  }
  __syncthreads();
  int c = tid & 15;
  int col = cb * 16 + c;
  int kq = tid >> 4;
  float acc[16];
#pragma unroll
  for (int b = 0; b < 16; ++b) acc[b] = 0.f;
  int kbase = kq4 * 256 + kq * 16;
  for (int k = kbase; k < kbase + 16; ++k) {
    float wv = Wq[(size_t)k * 1024 + col];
#pragma unroll
    for (int b = 0; b < 16; ++b) acc[b] = fmaf(b2f(xs[b][k]), wv, acc[b]);
  }
#pragma unroll
  for (int b = 0; b < 16; ++b) part[kq][b][c] = acc[b];
  __syncthreads();
  {
    int b = tid >> 4, cc = tid & 15;
    float s = 0.f;
#pragma unroll
    for (int j = 0; j < 16; ++j) s += part[j][b][cc];
    if (kq4 == 0) s += bq[cb * 16 + cc];
    qpart[kq4 * 16384 + b * 1024 + cb * 16 + cc] = s;
  }
}

// ---------------- qtg[b,h,j] = g_j * (Wk[:,h*64..] @ Q)[j]; bkq, Sg, Sb ----------
__global__ __launch_bounds__(256) void kq_k(const float* __restrict__ Wk,
                                            const float* __restrict__ bk,
                                            const float* __restrict__ qpart,
                                            const float* __restrict__ g,
                                            const float* __restrict__ bb,
                                            u16* __restrict__ qtb,
                                            float* __restrict__ bkq,
                                            float* __restrict__ Sg,
                                            float* __restrict__ Sb) {
  int h = blockIdx.x >> 2, jc = blockIdx.x & 3;
  int tid = threadIdx.x;
  __shared__ float Qs[16][64];
  __shared__ float rg[4][16], rb[4][16];
  for (int i = tid; i < 1024; i += 256) {
    int b = i >> 6, d = i & 63;
    int o = b * 1024 + h * 64 + d;
    Qs[b][d] = qpart[o] + qpart[16384 + o] + qpart[32768 + o] + qpart[49152 + o];
  }
  __syncthreads();
  int j = jc * 256 + tid;
  float acc[16];
#pragma unroll
  for (int b = 0; b < 16; ++b) acc[b] = 0.f;
  const float* wr = Wk + (size_t)j * 1024 + h * 64;
  for (int d4 = 0; d4 < 64; d4 += 4) {
    float4 w4 = *(const float4*)(wr + d4);
#pragma unroll
    for (int b = 0; b < 16; ++b) {
      acc[b] = fmaf(w4.x, Qs[b][d4], acc[b]);
      acc[b] = fmaf(w4.y, Qs[b][d4 + 1], acc[b]);
      acc[b] = fmaf(w4.z, Qs[b][d4 + 2], acc[b]);
      acc[b] = fmaf(w4.w, Qs[b][d4 + 3], acc[b]);
    }
  }
  float gj = g[j], bbj = bb[j];
  float sgp[16], sbp[16];
#pragma unroll
  for (int b = 0; b < 16; ++b) {
    u16 qg = f2b(acc[b] * gj);
    qtb[((size_t)b * 16 + h) * 1024 + j] = qg;
    sgp[b] = b2f(qg);            // match what the MFMA will see
    sbp[b] = acc[b] * bbj;
  }
#pragma unroll
  for (int off = 32; off; off >>= 1)
#pragma unroll
    for (int b = 0; b < 16; ++b) {
      sgp[b] += __shfl_down(sgp[b], off);
      sbp[b] += __shfl_down(sbp[b], off);
    }
  int lane = tid & 63, wv = tid >> 6;
  if (lane == 0)
#pragma unroll
    for (int b = 0; b < 16; ++b) { rg[wv][b] = sgp[b]; rb[wv][b] = sbp[b]; }
  __syncthreads();
  if (tid < 16) {
    int b = tid;
    atomicAdd(&Sg[b * 16 + h], rg[0][b] + rg[1][b] + rg[2][b] + rg[3][b]);
    atomicAdd(&Sb[b * 16 + h], rb[0][b] + rb[1][b] + rb[2][b] + rb[3][b]);
  }
  if (jc == 0 && tid < 16) {
    int b = tid;
    float s = 0.f;
    for (int d = 0; d < 64; ++d) s = fmaf(bk[h * 64 + d], Qs[b][d], s);
    bkq[b * 16 + h] = s;
  }
}

// ---------------- scores + y, grid 1024 = (b, 16-key group); k split over waves --
// Each of 4 waves covers the SAME 16 keys over its 256-k quarter; partial
// acc/acy/as1/as2 LDS-reduced; wave 0 does the LN-folded epilogue. Row stats
// via MFMA: Sx = mfma(afr,ones) (row-sum lands at own output slot), Sx2 =
// Gram diag mfma(afr,afr) + 1 shuffle.
__global__ __launch_bounds__(256) void score_k(
    const u16* __restrict__ x, const u16* __restrict__ qtb,
    const float* __restrict__ bkq, const int* __restrict__ mask,
    const u16* __restrict__ whi, const u16* __restrict__ wlo,
    const float* __restrict__ Sg, const float* __restrict__ Sb,
    const float* __restrict__ Swg, const float* __restrict__ Swb,
    float* __restrict__ sc, float* __restrict__ y) {
  int b = blockIdx.x >> 6, kg = blockIdx.x & 63;
  int tid = threadIdx.x;
  int l = tid & 63, w = tid >> 6;     // w = k-quarter
  int keybase = kg * 16;
  int lr = l & 15, ls = l >> 4;
  int masked = (mask[b * 1024 + 1023] == 0);

  bf16x8 ones;
#pragma unroll
  for (int j = 0; j < 8; ++j) ones[j] = (short)0x3F80;  // bf16 1.0

  f32x4 acc = (f32x4){0.f, 0.f, 0.f, 0.f};
  f32x4 acy = (f32x4){0.f, 0.f, 0.f, 0.f};
  f32x4 as1 = (f32x4){0.f, 0.f, 0.f, 0.f};
  f32x4 as2 = (f32x4){0.f, 0.f, 0.f, 0.f};
  const u16* xb = x + (size_t)b * 1024 * 1024;
  const u16* qb = qtb + (size_t)b * 16 * 1024;
  const int k0beg = w * 256;
  for (int k0 = k0beg; k0 < k0beg + 256; k0 += 32) {
    bf16x8 bfr = *(const bf16x8*)&qb[(size_t)lr * 1024 + k0 + ls * 8];
    bf16x8 bh  = *(const bf16x8*)&whi[(size_t)lr * 1024 + k0 + ls * 8];
    bf16x8 bl  = *(const bf16x8*)&wlo[(size_t)lr * 1024 + k0 + ls * 8];
    bf16x8 afr = *(const bf16x8*)&xb[(size_t)(keybase + lr) * 1024 + k0 + ls * 8];
    acc = __builtin_amdgcn_mfma_f32_16x16x32_bf16(afr, bfr, acc, 0, 0, 0);
    acy = __builtin_amdgcn_mfma_f32_16x16x32_bf16(afr, bh, acy, 0, 0, 0);
    acy = __builtin_amdgcn_mfma_f32_16x16x32_bf16(afr, bl, acy, 0, 0, 0);
    as1 = __builtin_amdgcn_mfma_f32_16x16x32_bf16(afr, ones, as1, 0, 0, 0);
    as2 = __builtin_amdgcn_mfma_f32_16x16x32_bf16(afr, afr, as2, 0, 0, 0);
  }

  __shared__ float red[3][64][16];
  if (w > 0) {
    float* r = red[w - 1][l];
#pragma unroll
    for (int q = 0; q < 4; ++q) {
      r[q] = acc[q]; r[4 + q] = acy[q]; r[8 + q] = as1[q]; r[12 + q] = as2[q];
    }
  }
  __syncthreads();
  if (w == 0) {
#pragma unroll
    for (int i = 0; i < 3; ++i) {
      const float* r = red[i][l];
#pragma unroll
      for (int q = 0; q < 4; ++q) {
        acc[q] += r[q]; acy[q] += r[4 + q]; as1[q] += r[8 + q]; as2[q] += r[12 + q];
      }
    }
    int h = lr;
    float bq_  = bkq[b * 16 + h];
    float Sgv  = Sg[b * 16 + h];
    float Sbv  = Sb[b * 16 + h];
    float Swgv = Swg[h];
    float Swbv = Swb[h];
#pragma unroll
    for (int q = 0; q < 4; ++q) {
      int key = keybase + ls * 4 + q;
      float s1 = as1[q];
      float s2 = __shfl(as2[q], ls * 4 + q + 16 * ls);
      float mean = s1 * (1.f / 1024.f);
      float var  = s2 * (1.f / 1024.f) - mean * mean;
      float rs   = rsqrtf(var + EPS);
      float sraw = rs * acc[q] - rs * mean * Sgv + Sbv + bq_;
      float v = masked ? 0.f : sraw * 0.125f;
      sc[((size_t)b * 16 + h) * 1024 + key] = v;
      y[((size_t)b * 16 + h) * 1024 + key] =
          rs * acy[q] - rs * mean * Swgv + Swbv;
    }
  }
}

// ---------------- fin: softmax(sc[bh]) . y[bh] -> atomicAdd out[b] (+bc once) ----
__global__ __launch_bounds__(256) void fin_k(const float* __restrict__ sc,
                                             const float* __restrict__ y,
                                             const float* __restrict__ bc,
                                             float* __restrict__ out) {
  int bh = blockIdx.x, tid = threadIdx.x;
  float4 v = ((const float4*)(sc + (size_t)bh * 1024))[tid];
  float m = fmaxf(fmaxf(v.x, v.y), fmaxf(v.z, v.w));
#pragma unroll
  for (int off = 32; off; off >>= 1) m = fmaxf(m, __shfl_down(m, off));
  __shared__ float rm[4], rs_[4], rd_[4];
  int lane = tid & 63, wv = tid >> 6;
  if (lane == 0) rm[wv] = m;
  __syncthreads();
  m = fmaxf(fmaxf(rm[0], rm[1]), fmaxf(rm[2], rm[3]));
  float e0 = expf(v.x - m), e1 = expf(v.y - m), e2 = expf(v.z - m), e3 = expf(v.w - m);
  float4 yv = ((const float4*)(y + (size_t)bh * 1024))[tid];
  float s = e0 + e1 + e2 + e3;
  float d = e0 * yv.x + e1 * yv.y + e2 * yv.z + e3 * yv.w;
#pragma unroll
  for (int off = 32; off; off >>= 1) {
    s += __shfl_down(s, off);
    d += __shfl_down(d, off);
  }
  if (lane == 0) { rs_[wv] = s; rd_[wv] = d; }
  __syncthreads();
  if (tid == 0) {
    float Z = rs_[0] + rs_[1] + rs_[2] + rs_[3];
    float D = rd_[0] + rd_[1] + rd_[2] + rd_[3];
    float add = D / Z;
    if ((bh & 15) == 0) add += bc[0];
    atomicAdd(&out[bh >> 4], add);
  }
}

extern "C" void kernel_launch(void* const* d_in, const int* in_sizes, int n_in,
                              void* d_out, int out_size, void* d_ws, size_t ws_size,
                              hipStream_t stream) {
  const int*   cate_x  = (const int*)d_in[0];
  const float* cont_x  = (const float*)d_in[1];
  const int*   mask    = (const int*)d_in[2];
  const float* emb     = (const float*)d_in[3];
  const float* cate_W  = (const float*)d_in[4];
  const float* cate_b  = (const float*)d_in[5];
  const float* cate_g  = (const float*)d_in[6];
  const float* cate_bb = (const float*)d_in[7];
  const float* bn_g    = (const float*)d_in[8];
  const float* bn_b    = (const float*)d_in[9];
  const float* cont_W  = (const float*)d_in[10];
  const float* cont_b  = (const float*)d_in[11];
  const float* cont_g  = (const float*)d_in[12];
  const float* cont_bb = (const float*)d_in[13];
  const float* Wq = (const float*)d_in[18]; const float* bq = (const float*)d_in[19];
  const float* Wk = (const float*)d_in[20]; const float* bk = (const float*)d_in[21];
  const float* Wv = (const float*)d_in[22]; const float* bv = (const float*)d_in[23];
  const float* Wo = (const float*)d_in[24]; const float* bo = (const float*)d_in[25];
  const float* comb_W  = (const float*)d_in[14];
  const float* comb_b  = (const float*)d_in[15];
  const float* comb_g  = (const float*)d_in[16];
  const float* comb_bb = (const float*)d_in[17];
  float* out = (float*)d_out;

  char* w = (char*)d_ws;
  float* part_bn = (float*)(w + 256);         // 64*16 f32 = 4KB
  u16* embb      = (u16*)(w + 131328);        // 1.25MB
  u16* cateWT    = (u16*)(w + 1411328);       // 1MB
  u16* combWT    = (u16*)(w + 2459904);       // 4MB
  float* sc      = (float*)(w + 6654208);     // 1MB scores
  u16*   qtb     = (u16*)(w + 7702784);       // 512KB
  float* bkq     = (float*)(w + 8292608);     // 1KB
  float* ybuf    = (float*)(w + 8388608);     // 1MB y
  u16* wvob_hi   = (u16*)(w + 9437184);       // 32KB
  u16* wvob_lo   = (u16*)(w + 9469952);       // 32KB
  float* qpart   = (float*)(w + 9506816);     // 256KB Q partials [4][16K]
  float* Sall    = (float*)(w + 10162176);    // Sg[256]|Sb[256]|Swg[16]|Swb[16]|bc
  float* Sg      = Sall;
  float* Sb      = Sall + 256;
  float* Swg     = Sall + 512;
  float* Swb     = Sall + 528;
  float* bc      = Sall + 552;                // 1 f32 (written by mid_k)
  u16* X1        = (u16*)(w + 10848512);      // 32MB
  u16* X2        = X1 + (size_t)16777216;     // 32MB
  u16* xb        = X2 + (size_t)16777216;     // 32MB (RAW gemm2 output, pre-LN)

  // preprocessing (zero out+Sall | BN partials | embconv | cateWT)
  prep_k<<<818, 256, 0, stream>>>(cont_x, part_bn, out, Sall, emb, embb,
                                  cate_W, cateWT);

  // cate: gathered-emb GEMM (K=512) -> X1
  gemm256<1><<<256, 512, 0, stream>>>(nullptr, nullptr, cate_x, embb, cateWT,
                                      cate_b, X1, 512);
  // fused: LN+ReLU(X1) | combWT | wvog hi/lo + Swg/Swb | cont -> X2 | bc
  mid_k<<<6721, 256, 0, stream>>>(X1, cate_g, cate_bb, comb_W, combWT, Wv, Wo,
                                  comb_g, comb_bb, wvob_hi, wvob_lo, Swg, Swb,
                                  bv, bo, bc, cont_x, part_bn, bn_g, bn_b,
                                  cont_W, cont_b, cont_g, cont_bb, X2);
  // combine: concat GEMM (K=2048) -> xb RAW (pre-LN)
  gemm256<2><<<256, 512, 0, stream>>>(X1, X2, nullptr, nullptr, combWT,
                                      comb_b, xb, 2048);

  // folded attention path (LN applied algebraically; stats computed in-kernel)
  qproj_k<<<256, 256, 0, stream>>>(xb, comb_g, comb_bb, Wq, bq, qpart);
  kq_k<<<64, 256, 0, stream>>>(Wk, bk, qpart, comb_g, comb_bb, qtb, bkq, Sg, Sb);
  score_k<<<1024, 256, 0, stream>>>(xb, qtb, bkq, mask, wvob_hi, wvob_lo,
                                    Sg, Sb, Swg, Swb, sc, ybuf);
  fin_k<<<256, 256, 0, stream>>>(sc, ybuf, bc, out);
}

// Round 12
// 174.482 us; speedup vs baseline: 1.1937x; 1.0391x over previous
//
#include <hip/hip_runtime.h>
#include <hip/hip_bf16.h>
#include <math.h>

// B=16, S=1024, CC=8, CF=8, E=64, H=1024, NH=16, DH=64, VOCAB=10000
// Output = out[:, -1:, -1] -> 16 f32
// Attention algebra: only query S-1 is needed. y[b,h,k]=x'_k.wvo_h folded into
// score; final LN(xb) folded algebraically (stats via MFMA in score_k, inline
// in qproj_k). Round-8 state + kq_k batch-split 64->256 blocks (last
// low-occupancy tail kernel; summand partition per (b,h) atomic unchanged).
// GEMMs frozen at round-3 form (72.0us, VGPR 116; round-5 regalloc lesson).
// Boundary lesson (rounds 4/9/10): a dispatch boundary costs ~3-5us; never
// pay for removing one with occupancy loss or redundant serial work.
#define EPS 1e-5f

typedef unsigned short u16;
typedef __attribute__((ext_vector_type(8))) short bf16x8;
typedef __attribute__((ext_vector_type(4))) float f32x4;

__device__ __forceinline__ float b2f(u16 u) {
  union { unsigned int i; float f; } v; v.i = ((unsigned int)u) << 16; return v.f;
}
__device__ __forceinline__ u16 f2b(float f) {
  union { float f; unsigned int i; } v; v.f = f;
  unsigned int r = v.i + 0x7fff + ((v.i >> 16) & 1);
  return (u16)(r >> 16);
}

__device__ __forceinline__ void gload_lds16(const u16* g, u16* l) {
  __builtin_amdgcn_global_load_lds(
      (const __attribute__((address_space(1))) unsigned int*)g,
      (__attribute__((address_space(3))) unsigned int*)l, 16, 0, 0);
}

// ---------------- preprocessing needed BEFORE gemm1 -----------------------------
__global__ __launch_bounds__(256) void prep_k(
    const float* __restrict__ cx, float* __restrict__ part_bn,
    float* __restrict__ out, float* __restrict__ Sall,
    const float* __restrict__ emb, u16* __restrict__ embb,
    const float* __restrict__ cate_W, u16* __restrict__ cateWT) {
  __shared__ float shmem[64 * 65];
  const int bid = blockIdx.x, tid = threadIdx.x;

  if (bid == 0) {
    if (tid < 16) out[tid] = 0.f;                        // d_out accumulator
    for (int i = tid; i < 544; i += 256) Sall[i] = 0.f;  // Sg|Sb|Swg|Swb
    return;
  }
  if (bid <= 64) {                       // BN partial sums
    int pb = bid - 1;
    int gid = pb * 256 + tid;
    float4 a = ((const float4*)cx)[2 * gid];
    float4 b = ((const float4*)cx)[2 * gid + 1];
    float v[16];
    v[0] = a.x; v[1] = a.y; v[2] = a.z; v[3] = a.w;
    v[4] = b.x; v[5] = b.y; v[6] = b.z; v[7] = b.w;
#pragma unroll
    for (int i = 0; i < 8; ++i) v[8 + i] = v[i] * v[i];
#pragma unroll
    for (int off = 32; off; off >>= 1)
#pragma unroll
      for (int i = 0; i < 16; ++i) v[i] += __shfl_down(v[i], off);
    int l = tid & 63, wv_ = tid >> 6;
    if (l == 0)
#pragma unroll
      for (int i = 0; i < 16; ++i) shmem[wv_ * 16 + i] = v[i];
    __syncthreads();
    if (tid < 16)
      part_bn[pb * 16 + tid] = shmem[tid] + shmem[16 + tid] + shmem[32 + tid] + shmem[48 + tid];
    return;
  }
  if (bid <= 689) {                      // embconv
    int i = (bid - 65) * 256 + tid;
    if (i < 160000) {
      float4 v = ((const float4*)emb)[i];
      ushort4 u; u.x = f2b(v.x); u.y = f2b(v.y); u.z = f2b(v.z); u.w = f2b(v.w);
      ((ushort4*)embb)[i] = u;
    }
    return;
  }
  {                                      // cateWT transpose fp32->bf16 (K=512)
    int local = bid - 690;
    int n0 = (local & 15) * 64, k0 = (local >> 4) * 64;
    int c = tid & 63, r0 = tid >> 6;
#pragma unroll
    for (int i = 0; i < 16; ++i) {
      int r = r0 + i * 4;
      shmem[r * 65 + c] = cate_W[(size_t)(k0 + r) * 1024 + n0 + c];
    }
    __syncthreads();
#pragma unroll
    for (int i = 0; i < 16; ++i) {
      int r = r0 + i * 4;
      cateWT[(size_t)(n0 + r) * 512 + k0 + c] = f2b(shmem[c * 65 + r]);
    }
  }
}

// ---------------- 256x256 MFMA GEMM, 8 waves, BK=64, 8-phase schedule -----------
// FROZEN round-3 kernel (72.0us, VGPR 116): XCD-chunked swizzle, 8-phase
// counted-vmcnt, MODE-1 sidx stash. No epilogue additions (round-5 lesson).
template <int MODE>
__global__ __launch_bounds__(512) void gemm256(
    const u16* __restrict__ A0, const u16* __restrict__ A1,
    const int* __restrict__ idx, const u16* __restrict__ embb,
    const u16* __restrict__ BT, const float* __restrict__ bias,
    u16* __restrict__ C, int K) {
  __shared__ u16 As[2][2][8192];
  __shared__ u16 Bs[2][2][8192];
  __shared__ int sidx[MODE == 1 ? 2048 : 4];
  const int tid = threadIdx.x;
  const int bid = blockIdx.x;
  const int chunk = gridDim.x >> 3;               // 32
  const int swz = (bid & 7) * chunk + (bid >> 3); // XCD-chunked, bijective
  const int row0 = (swz >> 2) * 256;
  const int col0 = (swz & 3) * 256;

  const int rr8 = tid >> 3;
  const int p8  = tid & 7;
  const int sl  = p8 ^ (rr8 & 7);

  const int l   = tid & 63;
  const int w   = tid >> 6;
  const int wrh = w >> 2;
  const int wcq = w & 3;
  const int hb  = wcq >> 1;
  const int rbb = (wcq & 1) * 64;
  const int lr  = l & 15;
  const int lk  = l >> 4;

  f32x4 acc[8][4];
#pragma unroll
  for (int m = 0; m < 8; ++m)
#pragma unroll
    for (int n = 0; n < 4; ++n) acc[m][n] = (f32x4){0.f, 0.f, 0.f, 0.f};

  const int nt = K >> 6;        // 8 (cate) or 32 (comb) -- always even
  const int nit = nt >> 1;

  if (MODE == 1) {              // stash all 256 rows x 8 k-chunk indices in LDS
    *(int4*)&sidx[tid * 4] = *(const int4*)&idx[row0 * 8 + tid * 4];
    __syncthreads();
  }

  auto stageA = [&](int t, int h) {               // one A half-tile: 2 loads
    const int k0 = t << 6;
    const int buf = t & 1;
#pragma unroll
    for (int i = 0; i < 2; ++i) {
      const u16* asrc;
      if (MODE == 1) {
        int id = sidx[(h * 128 + i * 64 + rr8) * 8 + (k0 >> 6)];
        asrc = embb + (size_t)id * 64 + sl * 8;
      } else {
        int ar = row0 + h * 128 + i * 64 + rr8;
        const u16* base = (k0 < 1024) ? A0 : A1;
        asrc = base + (size_t)ar * 1024 + (k0 & 1023) + sl * 8;
      }
      gload_lds16(asrc, &As[buf][h][i * 4096 + tid * 8]);
    }
  };
  auto stageB = [&](int t, int h) {               // one B half-tile: 2 loads
    const int k0 = t << 6;
    const int buf = t & 1;
#pragma unroll
    for (int i = 0; i < 2; ++i) {
      int br = col0 + h * 128 + i * 64 + rr8;
      gload_lds16(BT + (size_t)br * K + k0 + sl * 8,
                  &Bs[buf][h][i * 4096 + tid * 8]);
    }
  };

  bf16x8 bfr[4][2];
  auto loadB = [&](int buf) {                     // 8 ds_read_b128
#pragma unroll
    for (int n = 0; n < 4; ++n)
#pragma unroll
      for (int ks = 0; ks < 2; ++ks) {
        int rowb = rbb + n * 16 + lr;
        int ph = (ks * 4 + lk) ^ (lr & 7);
        bfr[n][ks] = *(const bf16x8*)&Bs[buf][hb][rowb * 64 + ph * 8];
      }
  };
  auto loadA = [&](bf16x8 (&af)[2][2], int buf, int q) {  // 4 ds_read_b128
#pragma unroll
    for (int mm = 0; mm < 2; ++mm)
#pragma unroll
      for (int ks = 0; ks < 2; ++ks) {
        int rowa = (q * 2 + mm) * 16 + lr;
        int ph = (ks * 4 + lk) ^ (lr & 7);
        af[mm][ks] = *(const bf16x8*)&As[buf][wrh][rowa * 64 + ph * 8];
      }
  };
  auto mfma_quad = [&](bf16x8 (&af)[2][2], int q) {       // 16 MFMA
    __builtin_amdgcn_s_setprio(1);
#pragma unroll
    for (int ks = 0; ks < 2; ++ks)
#pragma unroll
      for (int mm = 0; mm < 2; ++mm)
#pragma unroll
        for (int n = 0; n < 4; ++n)
          acc[q * 2 + mm][n] = __builtin_amdgcn_mfma_f32_16x16x32_bf16(
              af[mm][ks], bfr[n][ks], acc[q * 2 + mm][n], 0, 0, 0);
    __builtin_amdgcn_s_setprio(0);
  };

  // ---- prologue: tile0 A+B, tile1 B; wait tile0 (leave tile1-B in flight)
  stageA(0, 0); stageA(0, 1);
  stageB(0, 0); stageB(0, 1);
  stageB(1, 0); stageB(1, 1);
  asm volatile("s_waitcnt vmcnt(4)" ::: "memory");
  __builtin_amdgcn_s_barrier();

  for (int it = 0; it < nit; ++it) {
    const int T = it * 2;
    const bool more = (T + 2 < nt);     // also == (T+3 < nt) since nt even
    bf16x8 af[2][2];

    // -------- tile T (buf 0) --------
    loadB(0); loadA(af, 0, 0);
    stageA(T + 1, 0);
    __builtin_amdgcn_s_barrier();
    asm volatile("s_waitcnt lgkmcnt(0)" ::: "memory");
    mfma_quad(af, 0);
    __builtin_amdgcn_s_barrier();
    loadA(af, 0, 1);
    stageA(T + 1, 1);
    __builtin_amdgcn_s_barrier();
    asm volatile("s_waitcnt lgkmcnt(0)" ::: "memory");
    mfma_quad(af, 1);
    __builtin_amdgcn_s_barrier();
    loadA(af, 0, 2);
    if (more) stageB(T + 2, 0);
    __builtin_amdgcn_s_barrier();
    asm volatile("s_waitcnt lgkmcnt(0)" ::: "memory");
    mfma_quad(af, 2);
    __builtin_amdgcn_s_barrier();
    loadA(af, 0, 3);
    if (more) stageB(T + 2, 1);
    __builtin_amdgcn_s_barrier();
    asm volatile("s_waitcnt lgkmcnt(0)" ::: "memory");
    mfma_quad(af, 3);
    if (more) asm volatile("s_waitcnt vmcnt(4)" ::: "memory");
    else      asm volatile("s_waitcnt vmcnt(0)" ::: "memory");
    __builtin_amdgcn_s_barrier();

    // -------- tile T+1 (buf 1) --------
    loadB(1); loadA(af, 1, 0);
    if (more) stageA(T + 2, 0);
    __builtin_amdgcn_s_barrier();
    asm volatile("s_waitcnt lgkmcnt(0)" ::: "memory");
    mfma_quad(af, 0);
    __builtin_amdgcn_s_barrier();
    loadA(af, 1, 1);
    if (more) stageA(T + 2, 1);
    __builtin_amdgcn_s_barrier();
    asm volatile("s_waitcnt lgkmcnt(0)" ::: "memory");
    mfma_quad(af, 1);
    __builtin_amdgcn_s_barrier();
    loadA(af, 1, 2);
    if (more) stageB(T + 3, 0);
    __builtin_amdgcn_s_barrier();
    asm volatile("s_waitcnt lgkmcnt(0)" ::: "memory");
    mfma_quad(af, 2);
    __builtin_amdgcn_s_barrier();
    loadA(af, 1, 3);
    if (more) stageB(T + 3, 1);
    __builtin_amdgcn_s_barrier();
    asm volatile("s_waitcnt lgkmcnt(0)" ::: "memory");
    mfma_quad(af, 3);
    if (it + 1 < nit) {
      asm volatile("s_waitcnt vmcnt(4)" ::: "memory");
      __builtin_amdgcn_s_barrier();
    }
  }

  float bv_[4];
#pragma unroll
  for (int n = 0; n < 4; ++n) bv_[n] = bias[col0 + wcq * 64 + n * 16 + lr];
#pragma unroll
  for (int m = 0; m < 8; ++m) {
#pragma unroll
    for (int n = 0; n < 4; ++n) {
      int cc = col0 + wcq * 64 + n * 16 + lr;
#pragma unroll
      for (int q4 = 0; q4 < 4; ++q4) {
        int rr = row0 + wrh * 128 + m * 16 + lk * 4 + q4;
        C[(size_t)rr * 1024 + cc] = f2b(acc[m][n][q4] + bv_[n]);
      }
    }
  }
}

// ---------------- In-place LayerNorm body (used by mid_k for X1) ----------------
__device__ __forceinline__ void ln_body(u16* __restrict__ buf,
                                        const float* __restrict__ g,
                                        const float* __restrict__ b, int relu,
                                        int blk, int tid) {
  int lane = tid & 63, wave = tid >> 6;
  size_t row = (size_t)blk * 4 + wave;
  u16* p = buf + row * 1024 + lane * 16;
  uint4 u0 = *(uint4*)p;
  uint4 u1 = *(uint4*)(p + 8);
  float x[16];
#pragma unroll
  for (int i = 0; i < 4; ++i) {
    unsigned int w0 = ((unsigned int*)&u0)[i];
    unsigned int w1 = ((unsigned int*)&u1)[i];
    x[2 * i]     = b2f((u16)(w0 & 0xffff));
    x[2 * i + 1] = b2f((u16)(w0 >> 16));
    x[8 + 2 * i]     = b2f((u16)(w1 & 0xffff));
    x[8 + 2 * i + 1] = b2f((u16)(w1 >> 16));
  }
  float s = 0.f, s2 = 0.f;
#pragma unroll
  for (int i = 0; i < 16; ++i) { s += x[i]; s2 += x[i] * x[i]; }
#pragma unroll
  for (int off = 32; off; off >>= 1) { s += __shfl_xor(s, off); s2 += __shfl_xor(s2, off); }
  float mean = s * (1.f / 1024.f);
  float var = s2 * (1.f / 1024.f) - mean * mean;
  float rs = rsqrtf(var + EPS);
  float y[16];
#pragma unroll
  for (int q = 0; q < 4; ++q) {
    float4 gv = *(const float4*)(g + lane * 16 + q * 4);
    float4 bv = *(const float4*)(b + lane * 16 + q * 4);
    y[4 * q]     = (x[4 * q]     - mean) * rs * gv.x + bv.x;
    y[4 * q + 1] = (x[4 * q + 1] - mean) * rs * gv.y + bv.y;
    y[4 * q + 2] = (x[4 * q + 2] - mean) * rs * gv.z + bv.z;
    y[4 * q + 3] = (x[4 * q + 3] - mean) * rs * gv.w + bv.w;
  }
  if (relu)
#pragma unroll
    for (int i = 0; i < 16; ++i) y[i] = fmaxf(y[i], 0.f);
  uint4 o0, o1;
#pragma unroll
  for (int i = 0; i < 4; ++i) {
    ((unsigned int*)&o0)[i] = (unsigned int)f2b(y[2 * i]) | ((unsigned int)f2b(y[2 * i + 1]) << 16);
    ((unsigned int*)&o1)[i] = (unsigned int)f2b(y[8 + 2 * i]) | ((unsigned int)f2b(y[8 + 2 * i + 1]) << 16);
  }
  *(uint4*)p = o0;
  *(uint4*)(p + 8) = o1;
}

// ---------------- cont path body (BN -> Linear(8->1024) -> LN -> ReLU) ----------
__device__ __forceinline__ void cont_body(const float* __restrict__ cx,
                                          const float* __restrict__ part_bn,
                                          const float* __restrict__ bn_g,
                                          const float* __restrict__ bn_b,
                                          const float* __restrict__ W,
                                          const float* __restrict__ cb,
                                          const float* __restrict__ g,
                                          const float* __restrict__ bb,
                                          u16* __restrict__ out,
                                          int row0, int tid) {
  __shared__ float sp[4][16];
  __shared__ float tt[16];
  __shared__ float ab[2][8];
  __shared__ float xn[8][8];
  __shared__ float rr1[4][8], rr2[4][8];

  if (tid < 64) {
    int f = tid & 15, qd = tid >> 4;
    float s = 0.f;
    for (int j = qd * 16; j < qd * 16 + 16; ++j) s += part_bn[j * 16 + f];
    sp[qd][f] = s;
  }
  __syncthreads();
  if (tid < 16) tt[tid] = sp[0][tid] + sp[1][tid] + sp[2][tid] + sp[3][tid];
  __syncthreads();
  if (tid < 8) {
    float mu = tt[tid] * (1.f / 16384.f);
    float var = tt[8 + tid] * (1.f / 16384.f) - mu * mu;
    float a = rsqrtf(var + EPS) * bn_g[tid];
    ab[0][tid] = a;
    ab[1][tid] = bn_b[tid] - mu * a;
  }
  __syncthreads();
  if (tid < 64) {
    int r = tid >> 3, f = tid & 7;
    xn[r][f] = ab[0][f] * cx[(row0 + r) * 8 + f] + ab[1][f];
  }
  __syncthreads();

  int c = tid * 4;
  float4 cbv = *(const float4*)(cb + c);
  float acc[8][4];
#pragma unroll
  for (int r = 0; r < 8; ++r) {
    acc[r][0] = cbv.x; acc[r][1] = cbv.y; acc[r][2] = cbv.z; acc[r][3] = cbv.w;
  }
  for (int k = 0; k < 8; ++k) {
    float4 w4 = *(const float4*)(W + k * 1024 + c);
#pragma unroll
    for (int r = 0; r < 8; ++r) {
      float xv = xn[r][k];
      acc[r][0] = fmaf(xv, w4.x, acc[r][0]);
      acc[r][1] = fmaf(xv, w4.y, acc[r][1]);
      acc[r][2] = fmaf(xv, w4.z, acc[r][2]);
      acc[r][3] = fmaf(xv, w4.w, acc[r][3]);
    }
  }
  float s1[8], s2[8];
#pragma unroll
  for (int r = 0; r < 8; ++r) {
    s1[r] = acc[r][0] + acc[r][1] + acc[r][2] + acc[r][3];
    s2[r] = acc[r][0] * acc[r][0] + acc[r][1] * acc[r][1] +
            acc[r][2] * acc[r][2] + acc[r][3] * acc[r][3];
  }
#pragma unroll
  for (int off = 32; off; off >>= 1)
#pragma unroll
    for (int r = 0; r < 8; ++r) {
      s1[r] += __shfl_down(s1[r], off);
      s2[r] += __shfl_down(s2[r], off);
    }
  int lane = tid & 63, wv = tid >> 6;
  if (lane == 0)
#pragma unroll
    for (int r = 0; r < 8; ++r) { rr1[wv][r] = s1[r]; rr2[wv][r] = s2[r]; }
  __syncthreads();
  float4 gv = *(const float4*)(g + c);
  float4 bv = *(const float4*)(bb + c);
#pragma unroll
  for (int r = 0; r < 8; ++r) {
    float ss = rr1[0][r] + rr1[1][r] + rr1[2][r] + rr1[3][r];
    float qq = rr2[0][r] + rr2[1][r] + rr2[2][r] + rr2[3][r];
    float mean = ss * (1.f / 1024.f);
    float var = qq * (1.f / 1024.f) - mean * mean;
    float rs = rsqrtf(var + EPS);
    float y0 = fmaxf((acc[r][0] - mean) * rs * gv.x + bv.x, 0.f);
    float y1 = fmaxf((acc[r][1] - mean) * rs * gv.y + bv.y, 0.f);
    float y2 = fmaxf((acc[r][2] - mean) * rs * gv.z + bv.z, 0.f);
    float y3 = fmaxf((acc[r][3] - mean) * rs * gv.w + bv.w, 0.f);
    ushort4 o; o.x = f2b(y0); o.y = f2b(y1); o.z = f2b(y2); o.w = f2b(y3);
    *(ushort4*)(out + (size_t)(row0 + r) * 1024 + c) = o;
  }
}

// ---------------- fused mid dispatch ---------------------------------------------
// grid: [0,4096) ln(X1) | [4096,4608) combWT | [4608,4672) wvog | [4672,6720) cont
//       | 6720 bc = bv.Wo[:,1023] + bo[1023]
__global__ __launch_bounds__(256) void mid_k(
    u16* __restrict__ X1, const float* __restrict__ cate_g,
    const float* __restrict__ cate_bb,
    const float* __restrict__ comb_W, u16* __restrict__ combWT,
    const float* __restrict__ Wv, const float* __restrict__ Wo,
    const float* __restrict__ comb_g, const float* __restrict__ comb_bbv,
    u16* __restrict__ wvob_hi, u16* __restrict__ wvob_lo,
    float* __restrict__ Swg, float* __restrict__ Swb,
    const float* __restrict__ bv, const float* __restrict__ bo,
    float* __restrict__ bc,
    const float* __restrict__ cx, const float* __restrict__ part_bn,
    const float* __restrict__ bn_g, const float* __restrict__ bn_b,
    const float* __restrict__ cont_W, const float* __restrict__ cont_b,
    const float* __restrict__ cont_g, const float* __restrict__ cont_bb,
    u16* __restrict__ X2) {
  __shared__ float shmem[64 * 65];
  const int bid = blockIdx.x, tid = threadIdx.x;
  if (bid < 4096) {                      // LN(X1) + ReLU
    ln_body(X1, cate_g, cate_bb, 1, bid, tid);
    return;
  }
  if (bid < 4608) {                      // combWT transpose fp32->bf16 (K=2048)
    int local = bid - 4096;
    int n0 = (local & 15) * 64, k0 = (local >> 4) * 64;
    int c = tid & 63, r0 = tid >> 6;
#pragma unroll
    for (int i = 0; i < 16; ++i) {
      int r = r0 + i * 4;
      shmem[r * 65 + c] = comb_W[(size_t)(k0 + r) * 1024 + n0 + c];
    }
    __syncthreads();
#pragma unroll
    for (int i = 0; i < 16; ++i) {
      int r = r0 + i * 4;
      combWT[(size_t)(n0 + r) * 2048 + k0 + c] = f2b(shmem[c * 65 + r]);
    }
    return;
  }
  if (bid < 4672) {                      // wvog (bf16 hi+lo), Swg/Swb
    int local = bid - 4608;
    int h = local >> 2, jc = local & 3;
    if (tid < 64) shmem[tid] = Wo[(size_t)(h * 64 + tid) * 1024 + 1023];
    __syncthreads();
    int j = jc * 256 + tid;
    const float* vr = Wv + (size_t)j * 1024 + h * 64;
    float s = 0.f;
    for (int d4 = 0; d4 < 64; d4 += 4) {
      float4 w4 = *(const float4*)(vr + d4);
      s = fmaf(w4.x, shmem[d4], s);
      s = fmaf(w4.y, shmem[d4 + 1], s);
      s = fmaf(w4.z, shmem[d4 + 2], s);
      s = fmaf(w4.w, shmem[d4 + 3], s);
    }
    float sg_ = s * comb_g[j];
    u16 hi = f2b(sg_);
    float lo = sg_ - b2f(hi);
    wvob_hi[h * 1024 + j] = hi;
    wvob_lo[h * 1024 + j] = f2b(lo);
    float swgp = sg_;
    float swbp = s * comb_bbv[j];
#pragma unroll
    for (int off = 32; off; off >>= 1) {
      swgp += __shfl_down(swgp, off);
      swbp += __shfl_down(swbp, off);
    }
    int lane = tid & 63, wv = tid >> 6;
    if (lane == 0) { shmem[64 + wv] = swgp; shmem[68 + wv] = swbp; }
    __syncthreads();
    if (tid == 0) {
      atomicAdd(&Swg[h], shmem[64] + shmem[65] + shmem[66] + shmem[67]);
      atomicAdd(&Swb[h], shmem[68] + shmem[69] + shmem[70] + shmem[71]);
    }
    return;
  }
  if (bid < 6720) {                      // cont path -> X2
    int row0 = (bid - 4672) * 8;
    cont_body(cx, part_bn, bn_g, bn_b, cont_W, cont_b, cont_g, cont_bb, X2,
              row0, tid);
    return;
  }
  {                                      // bc = bv . Wo[:,1023] + bo[1023]
    float s = 0.f;
    for (int i = tid; i < 1024; i += 256)
      s = fmaf(bv[i], Wo[(size_t)i * 1024 + 1023], s);
#pragma unroll
    for (int off = 32; off; off >>= 1) s += __shfl_down(s, off);
    int lane = tid & 63, wv = tid >> 6;
    if (lane == 0) shmem[wv] = s;
    __syncthreads();
    if (tid == 0) bc[0] = shmem[0] + shmem[1] + shmem[2] + shmem[3] + bo[1023];
  }
}

// ---------------- Q projection partials, grid 256 = (colblk 0..63, kq4 0..3) ----
// Each block: stage+LN its 16 rows (stats recomputed redundantly, L2-hot),
// compute partial Q over its 256-k quarter, write qpart[kq4]. bq folded into
// partial 0. kq_k sums the 4 partials.
__global__ __launch_bounds__(256) void qproj_k(const u16* __restrict__ x,
                                               const float* __restrict__ g,
                                               const float* __restrict__ bb,
                                               const float* __restrict__ Wq,
                                               const float* __restrict__ bq,
                                               float* __restrict__ qpart) {
  __shared__ u16 xs[16][1024];
  __shared__ float part[16][16][16];
  __shared__ float ps1[16][16], ps2[16][16];
  __shared__ float sm[16], sr[16];
  int tid = threadIdx.x;
  int cb = blockIdx.x >> 2, kq4 = blockIdx.x & 3;
  // stage raw rows (b, 1023)
  for (int i = tid; i < 4096; i += 256) {
    int b = i >> 8, off = (i & 255) * 4;
    *(ushort4*)&xs[b][off] =
        *(const ushort4*)(x + ((size_t)(b * 1024 + 1023)) * 1024 + off);
  }
  __syncthreads();
  // per-row LN stats: 16 threads/row, 64 cols each
  {
    int b = tid >> 4, seg = tid & 15;
    float s = 0.f, s2 = 0.f;
    for (int k = seg * 64; k < seg * 64 + 64; ++k) {
      float v = b2f(xs[b][k]);
      s += v;
      s2 = fmaf(v, v, s2);
    }
    ps1[b][seg] = s;
    ps2[b][seg] = s2;
  }
  __syncthreads();
  if (tid < 16) {
    float s = 0.f, s2 = 0.f;
#pragma unroll
    for (int j = 0; j < 16; ++j) { s += ps1[tid][j]; s2 += ps2[tid][j]; }
    float mean = s * (1.f / 1024.f);
    float var = s2 * (1.f / 1024.f) - mean * mean;
    sm[tid] = mean;
    sr[tid] = rsqrtf(var + EPS);
  }
  __syncthreads();
  // normalize in place
  for (int i = tid; i < 4096; i += 256) {
    int b = i >> 8, off = (i & 255) * 4;
    ushort4 u = *(ushort4*)&xs[b][off];
    float4 gv = *(const float4*)(g + off);
    float4 bvv = *(const float4*)(bb + off);
    float m = sm[b], r = sr[b];
    ushort4 o;
    o.x = f2b((b2f(u.x) - m) * r * gv.x + bvv.x);
    o.y = f2b((b2f(u.y) - m) * r * gv.y + bvv.y);
    o.z = f2b((b2f(u.z) - m) * r * gv.z + bvv.z);
    o.w = f2b((b2f(u.w) - m) * r * gv.w + bvv.w);
    *(ushort4*)&xs[b][off] = o;
  }
  __syncthreads();
  int c = tid & 15;
  int col = cb * 16 + c;
  int kq = tid >> 4;
  float acc[16];
#pragma unroll
  for (int b = 0; b < 16; ++b) acc[b] = 0.f;
  int kbase = kq4 * 256 + kq * 16;
  for (int k = kbase; k < kbase + 16; ++k) {
    float wv = Wq[(size_t)k * 1024 + col];
#pragma unroll
    for (int b = 0; b < 16; ++b) acc[b] = fmaf(b2f(xs[b][k]), wv, acc[b]);
  }
#pragma unroll
  for (int b = 0; b < 16; ++b) part[kq][b][c] = acc[b];
  __syncthreads();
  {
    int b = tid >> 4, cc = tid & 15;
    float s = 0.f;
#pragma unroll
    for (int j = 0; j < 16; ++j) s += part[j][b][cc];
    if (kq4 == 0) s += bq[cb * 16 + cc];
    qpart[kq4 * 16384 + b * 1024 + cb * 16 + cc] = s;
  }
}

// ---------------- qtg[b,h,j] = g_j * (Wk[:,h*64..] @ Q)[j]; bkq, Sg, Sb ----------
// grid 256 = (h 0..15, jc 0..3, bg 0..3): batch split x4 vs round-8 (same
// summand partition per (b,h) atomic -- one add per jc -- values identical).
__global__ __launch_bounds__(256) void kq_k(const float* __restrict__ Wk,
                                            const float* __restrict__ bk,
                                            const float* __restrict__ qpart,
                                            const float* __restrict__ g,
                                            const float* __restrict__ bb,
                                            u16* __restrict__ qtb,
                                            float* __restrict__ bkq,
                                            float* __restrict__ Sg,
                                            float* __restrict__ Sb) {
  int h = blockIdx.x >> 4, jc = (blockIdx.x >> 2) & 3, bg = blockIdx.x & 3;
  int tid = threadIdx.x;
  __shared__ float Qs[4][64];
  __shared__ float rg[4][4], rb[4][4];
  if (tid < 256) {                       // 256 elements: one per thread
    int bl = tid >> 6, d = tid & 63;
    int o = (bg * 4 + bl) * 1024 + h * 64 + d;
    Qs[bl][d] = qpart[o] + qpart[16384 + o] + qpart[32768 + o] + qpart[49152 + o];
  }
  __syncthreads();
  int j = jc * 256 + tid;
  float acc[4];
#pragma unroll
  for (int bl = 0; bl < 4; ++bl) acc[bl] = 0.f;
  const float* wr = Wk + (size_t)j * 1024 + h * 64;
  for (int d4 = 0; d4 < 64; d4 += 4) {
    float4 w4 = *(const float4*)(wr + d4);
#pragma unroll
    for (int bl = 0; bl < 4; ++bl) {
      acc[bl] = fmaf(w4.x, Qs[bl][d4], acc[bl]);
      acc[bl] = fmaf(w4.y, Qs[bl][d4 + 1], acc[bl]);
      acc[bl] = fmaf(w4.z, Qs[bl][d4 + 2], acc[bl]);
      acc[bl] = fmaf(w4.w, Qs[bl][d4 + 3], acc[bl]);
    }
  }
  float gj = g[j], bbj = bb[j];
  float sgp[4], sbp[4];
#pragma unroll
  for (int bl = 0; bl < 4; ++bl) {
    int b = bg * 4 + bl;
    u16 qg = f2b(acc[bl] * gj);
    qtb[((size_t)b * 16 + h) * 1024 + j] = qg;
    sgp[bl] = b2f(qg);           // match what the MFMA will see
    sbp[bl] = acc[bl] * bbj;
  }
#pragma unroll
  for (int off = 32; off; off >>= 1)
#pragma unroll
    for (int bl = 0; bl < 4; ++bl) {
      sgp[bl] += __shfl_down(sgp[bl], off);
      sbp[bl] += __shfl_down(sbp[bl], off);
    }
  int lane = tid & 63, wv = tid >> 6;
  if (lane == 0)
#pragma unroll
    for (int bl = 0; bl < 4; ++bl) { rg[wv][bl] = sgp[bl]; rb[wv][bl] = sbp[bl]; }
  __syncthreads();
  if (tid < 4) {
    int bl = tid, b = bg * 4 + bl;
    atomicAdd(&Sg[b * 16 + h], rg[0][bl] + rg[1][bl] + rg[2][bl] + rg[3][bl]);
    atomicAdd(&Sb[b * 16 + h], rb[0][bl] + rb[1][bl] + rb[2][bl] + rb[3][bl]);
  }
  if (jc == 0 && tid < 4) {
    int bl = tid, b = bg * 4 + bl;
    float s = 0.f;
    for (int d = 0; d < 64; ++d) s = fmaf(bk[h * 64 + d], Qs[bl][d], s);
    bkq[b * 16 + h] = s;
  }
}

// ---------------- scores + y, grid 1024 = (b, 16-key group); k split over waves --
// Each of 4 waves covers the SAME 16 keys over its 256-k quarter; partial
// acc/acy/as1/as2 LDS-reduced; wave 0 does the LN-folded epilogue. Row stats
// via MFMA: Sx = mfma(afr,ones) (row-sum lands at own output slot), Sx2 =
// Gram diag mfma(afr,afr) + 1 shuffle.
__global__ __launch_bounds__(256) void score_k(
    const u16* __restrict__ x, const u16* __restrict__ qtb,
    const float* __restrict__ bkq, const int* __restrict__ mask,
    const u16* __restrict__ whi, const u16* __restrict__ wlo,
    const float* __restrict__ Sg, const float* __restrict__ Sb,
    const float* __restrict__ Swg, const float* __restrict__ Swb,
    float* __restrict__ sc, float* __restrict__ y) {
  int b = blockIdx.x >> 6, kg = blockIdx.x & 63;
  int tid = threadIdx.x;
  int l = tid & 63, w = tid >> 6;     // w = k-quarter
  int keybase = kg * 16;
  int lr = l & 15, ls = l >> 4;
  int masked = (mask[b * 1024 + 1023] == 0);

  bf16x8 ones;
#pragma unroll
  for (int j = 0; j < 8; ++j) ones[j] = (short)0x3F80;  // bf16 1.0

  f32x4 acc = (f32x4){0.f, 0.f, 0.f, 0.f};
  f32x4 acy = (f32x4){0.f, 0.f, 0.f, 0.f};
  f32x4 as1 = (f32x4){0.f, 0.f, 0.f, 0.f};
  f32x4 as2 = (f32x4){0.f, 0.f, 0.f, 0.f};
  const u16* xb = x + (size_t)b * 1024 * 1024;
  const u16* qb = qtb + (size_t)b * 16 * 1024;
  const int k0beg = w * 256;
  for (int k0 = k0beg; k0 < k0beg + 256; k0 += 32) {
    bf16x8 bfr = *(const bf16x8*)&qb[(size_t)lr * 1024 + k0 + ls * 8];
    bf16x8 bh  = *(const bf16x8*)&whi[(size_t)lr * 1024 + k0 + ls * 8];
    bf16x8 bl  = *(const bf16x8*)&wlo[(size_t)lr * 1024 + k0 + ls * 8];
    bf16x8 afr = *(const bf16x8*)&xb[(size_t)(keybase + lr) * 1024 + k0 + ls * 8];
    acc = __builtin_amdgcn_mfma_f32_16x16x32_bf16(afr, bfr, acc, 0, 0, 0);
    acy = __builtin_amdgcn_mfma_f32_16x16x32_bf16(afr, bh, acy, 0, 0, 0);
    acy = __builtin_amdgcn_mfma_f32_16x16x32_bf16(afr, bl, acy, 0, 0, 0);
    as1 = __builtin_amdgcn_mfma_f32_16x16x32_bf16(afr, ones, as1, 0, 0, 0);
    as2 = __builtin_amdgcn_mfma_f32_16x16x32_bf16(afr, afr, as2, 0, 0, 0);
  }

  __shared__ float red[3][64][16];
  if (w > 0) {
    float* r = red[w - 1][l];
#pragma unroll
    for (int q = 0; q < 4; ++q) {
      r[q] = acc[q]; r[4 + q] = acy[q]; r[8 + q] = as1[q]; r[12 + q] = as2[q];
    }
  }
  __syncthreads();
  if (w == 0) {
#pragma unroll
    for (int i = 0; i < 3; ++i) {
      const float* r = red[i][l];
#pragma unroll
      for (int q = 0; q < 4; ++q) {
        acc[q] += r[q]; acy[q] += r[4 + q]; as1[q] += r[8 + q]; as2[q] += r[12 + q];
      }
    }
    int h = lr;
    float bq_  = bkq[b * 16 + h];
    float Sgv  = Sg[b * 16 + h];
    float Sbv  = Sb[b * 16 + h];
    float Swgv = Swg[h];
    float Swbv = Swb[h];
#pragma unroll
    for (int q = 0; q < 4; ++q) {
      int key = keybase + ls * 4 + q;
      float s1 = as1[q];
      float s2 = __shfl(as2[q], ls * 4 + q + 16 * ls);
      float mean = s1 * (1.f / 1024.f);
      float var  = s2 * (1.f / 1024.f) - mean * mean;
      float rs   = rsqrtf(var + EPS);
      float sraw = rs * acc[q] - rs * mean * Sgv + Sbv + bq_;
      float v = masked ? 0.f : sraw * 0.125f;
      sc[((size_t)b * 16 + h) * 1024 + key] = v;
      y[((size_t)b * 16 + h) * 1024 + key] =
          rs * acy[q] - rs * mean * Swgv + Swbv;
    }
  }
}

// ---------------- fin: softmax(sc[bh]) . y[bh] -> atomicAdd out[b] (+bc once) ----
__global__ __launch_bounds__(256) void fin_k(const float* __restrict__ sc,
                                             const float* __restrict__ y,
                                             const float* __restrict__ bc,
                                             float* __restrict__ out) {
  int bh = blockIdx.x, tid = threadIdx.x;
  float4 v = ((const float4*)(sc + (size_t)bh * 1024))[tid];
  float m = fmaxf(fmaxf(v.x, v.y), fmaxf(v.z, v.w));
#pragma unroll
  for (int off = 32; off; off >>= 1) m = fmaxf(m, __shfl_down(m, off));
  __shared__ float rm[4], rs_[4], rd_[4];
  int lane = tid & 63, wv = tid >> 6;
  if (lane == 0) rm[wv] = m;
  __syncthreads();
  m = fmaxf(fmaxf(rm[0], rm[1]), fmaxf(rm[2], rm[3]));
  float e0 = expf(v.x - m), e1 = expf(v.y - m), e2 = expf(v.z - m), e3 = expf(v.w - m);
  float4 yv = ((const float4*)(y + (size_t)bh * 1024))[tid];
  float s = e0 + e1 + e2 + e3;
  float d = e0 * yv.x + e1 * yv.y + e2 * yv.z + e3 * yv.w;
#pragma unroll
  for (int off = 32; off; off >>= 1) {
    s += __shfl_down(s, off);
    d += __shfl_down(d, off);
  }
  if (lane == 0) { rs_[wv] = s; rd_[wv] = d; }
  __syncthreads();
  if (tid == 0) {
    float Z = rs_[0] + rs_[1] + rs_[2] + rs_[3];
    float D = rd_[0] + rd_[1] + rd_[2] + rd_[3];
    float add = D / Z;
    if ((bh & 15) == 0) add += bc[0];
    atomicAdd(&out[bh >> 4], add);
  }
}

extern "C" void kernel_launch(void* const* d_in, const int* in_sizes, int n_in,
                              void* d_out, int out_size, void* d_ws, size_t ws_size,
                              hipStream_t stream) {
  const int*   cate_x  = (const int*)d_in[0];
  const float* cont_x  = (const float*)d_in[1];
  const int*   mask    = (const int*)d_in[2];
  const float* emb     = (const float*)d_in[3];
  const float* cate_W  = (const float*)d_in[4];
  const float* cate_b  = (const float*)d_in[5];
  const float* cate_g  = (const float*)d_in[6];
  const float* cate_bb = (const float*)d_in[7];
  const float* bn_g    = (const float*)d_in[8];
  const float* bn_b    = (const float*)d_in[9];
  const float* cont_W  = (const float*)d_in[10];
  const float* cont_b  = (const float*)d_in[11];
  const float* cont_g  = (const float*)d_in[12];
  const float* cont_bb = (const float*)d_in[13];
  const float* Wq = (const float*)d_in[18]; const float* bq = (const float*)d_in[19];
  const float* Wk = (const float*)d_in[20]; const float* bk = (const float*)d_in[21];
  const float* Wv = (const float*)d_in[22]; const float* bv = (const float*)d_in[23];
  const float* Wo = (const float*)d_in[24]; const float* bo = (const float*)d_in[25];
  const float* comb_W  = (const float*)d_in[14];
  const float* comb_b  = (const float*)d_in[15];
  const float* comb_g  = (const float*)d_in[16];
  const float* comb_bb = (const float*)d_in[17];
  float* out = (float*)d_out;

  char* w = (char*)d_ws;
  float* part_bn = (float*)(w + 256);         // 64*16 f32 = 4KB
  u16* embb      = (u16*)(w + 131328);        // 1.25MB
  u16* cateWT    = (u16*)(w + 1411328);       // 1MB
  u16* combWT    = (u16*)(w + 2459904);       // 4MB
  float* sc      = (float*)(w + 6654208);     // 1MB scores
  u16*   qtb     = (u16*)(w + 7702784);       // 512KB
  float* bkq     = (float*)(w + 8292608);     // 1KB
  float* ybuf    = (float*)(w + 8388608);     // 1MB y
  u16* wvob_hi   = (u16*)(w + 9437184);       // 32KB
  u16* wvob_lo   = (u16*)(w + 9469952);       // 32KB
  float* qpart   = (float*)(w + 9506816);     // 256KB Q partials [4][16K]
  float* Sall    = (float*)(w + 10162176);    // Sg[256]|Sb[256]|Swg[16]|Swb[16]|bc
  float* Sg      = Sall;
  float* Sb      = Sall + 256;
  float* Swg     = Sall + 512;
  float* Swb     = Sall + 528;
  float* bc      = Sall + 552;                // 1 f32 (written by mid_k)
  u16* X1        = (u16*)(w + 10848512);      // 32MB
  u16* X2        = X1 + (size_t)16777216;     // 32MB
  u16* xb        = X2 + (size_t)16777216;     // 32MB (RAW gemm2 output, pre-LN)

  // preprocessing (zero out+Sall | BN partials | embconv | cateWT)
  prep_k<<<818, 256, 0, stream>>>(cont_x, part_bn, out, Sall, emb, embb,
                                  cate_W, cateWT);

  // cate: gathered-emb GEMM (K=512) -> X1
  gemm256<1><<<256, 512, 0, stream>>>(nullptr, nullptr, cate_x, embb, cateWT,
                                      cate_b, X1, 512);
  // fused: LN+ReLU(X1) | combWT | wvog hi/lo + Swg/Swb | cont -> X2 | bc
  mid_k<<<6721, 256, 0, stream>>>(X1, cate_g, cate_bb, comb_W, combWT, Wv, Wo,
                                  comb_g, comb_bb, wvob_hi, wvob_lo, Swg, Swb,
                                  bv, bo, bc, cont_x, part_bn, bn_g, bn_b,
                                  cont_W, cont_b, cont_g, cont_bb, X2);
  // combine: concat GEMM (K=2048) -> xb RAW (pre-LN)
  gemm256<2><<<256, 512, 0, stream>>>(X1, X2, nullptr, nullptr, combWT,
                                      comb_b, xb, 2048);

  // folded attention path (LN applied algebraically; stats computed in-kernel)
  qproj_k<<<256, 256, 0, stream>>>(xb, comb_g, comb_bb, Wq, bq, qpart);
  kq_k<<<256, 256, 0, stream>>>(Wk, bk, qpart, comb_g, comb_bb, qtb, bkq, Sg, Sb);
  score_k<<<1024, 256, 0, stream>>>(xb, qtb, bkq, mask, wvob_hi, wvob_lo,
                                    Sg, Sb, Swg, Swb, sc, ybuf);
  fin_k<<<256, 256, 0, stream>>>(sc, ybuf, bc, out);
}

// Round 13
// 173.935 us; speedup vs baseline: 1.1975x; 1.0031x over previous
//
#include <hip/hip_runtime.h>
#include <hip/hip_bf16.h>
#include <math.h>

// B=16, S=1024, CC=8, CF=8, E=64, H=1024, NH=16, DH=64, VOCAB=10000
// Output = out[:, -1:, -1] -> 16 f32
// Attention algebra: only query S-1 is needed. y[b,h,k]=x'_k.wvo_h folded into
// score; final LN(xb) folded algebraically (stats via MFMA in score_k, inline
// in qproj_k). Round-12 state (174.5us verified) + qproj_k stats loop
// vectorized (ushort4 LDS reads, 64->16 iters -- same serial-chain defect
// class that made kq_k slow). GEMMs frozen at round-3 form (72.0us, VGPR 116;
// round-5 regalloc lesson). Boundary lesson (rounds 4/9/10): a dispatch
// boundary costs ~3-5us; never pay for removing one with occupancy loss or
// redundant serial work.
#define EPS 1e-5f

typedef unsigned short u16;
typedef __attribute__((ext_vector_type(8))) short bf16x8;
typedef __attribute__((ext_vector_type(4))) float f32x4;

__device__ __forceinline__ float b2f(u16 u) {
  union { unsigned int i; float f; } v; v.i = ((unsigned int)u) << 16; return v.f;
}
__device__ __forceinline__ u16 f2b(float f) {
  union { float f; unsigned int i; } v; v.f = f;
  unsigned int r = v.i + 0x7fff + ((v.i >> 16) & 1);
  return (u16)(r >> 16);
}

__device__ __forceinline__ void gload_lds16(const u16* g, u16* l) {
  __builtin_amdgcn_global_load_lds(
      (const __attribute__((address_space(1))) unsigned int*)g,
      (__attribute__((address_space(3))) unsigned int*)l, 16, 0, 0);
}

// ---------------- preprocessing needed BEFORE gemm1 -----------------------------
__global__ __launch_bounds__(256) void prep_k(
    const float* __restrict__ cx, float* __restrict__ part_bn,
    float* __restrict__ out, float* __restrict__ Sall,
    const float* __restrict__ emb, u16* __restrict__ embb,
    const float* __restrict__ cate_W, u16* __restrict__ cateWT) {
  __shared__ float shmem[64 * 65];
  const int bid = blockIdx.x, tid = threadIdx.x;

  if (bid == 0) {
    if (tid < 16) out[tid] = 0.f;                        // d_out accumulator
    for (int i = tid; i < 544; i += 256) Sall[i] = 0.f;  // Sg|Sb|Swg|Swb
    return;
  }
  if (bid <= 64) {                       // BN partial sums
    int pb = bid - 1;
    int gid = pb * 256 + tid;
    float4 a = ((const float4*)cx)[2 * gid];
    float4 b = ((const float4*)cx)[2 * gid + 1];
    float v[16];
    v[0] = a.x; v[1] = a.y; v[2] = a.z; v[3] = a.w;
    v[4] = b.x; v[5] = b.y; v[6] = b.z; v[7] = b.w;
#pragma unroll
    for (int i = 0; i < 8; ++i) v[8 + i] = v[i] * v[i];
#pragma unroll
    for (int off = 32; off; off >>= 1)
#pragma unroll
      for (int i = 0; i < 16; ++i) v[i] += __shfl_down(v[i], off);
    int l = tid & 63, wv_ = tid >> 6;
    if (l == 0)
#pragma unroll
      for (int i = 0; i < 16; ++i) shmem[wv_ * 16 + i] = v[i];
    __syncthreads();
    if (tid < 16)
      part_bn[pb * 16 + tid] = shmem[tid] + shmem[16 + tid] + shmem[32 + tid] + shmem[48 + tid];
    return;
  }
  if (bid <= 689) {                      // embconv
    int i = (bid - 65) * 256 + tid;
    if (i < 160000) {
      float4 v = ((const float4*)emb)[i];
      ushort4 u; u.x = f2b(v.x); u.y = f2b(v.y); u.z = f2b(v.z); u.w = f2b(v.w);
      ((ushort4*)embb)[i] = u;
    }
    return;
  }
  {                                      // cateWT transpose fp32->bf16 (K=512)
    int local = bid - 690;
    int n0 = (local & 15) * 64, k0 = (local >> 4) * 64;
    int c = tid & 63, r0 = tid >> 6;
#pragma unroll
    for (int i = 0; i < 16; ++i) {
      int r = r0 + i * 4;
      shmem[r * 65 + c] = cate_W[(size_t)(k0 + r) * 1024 + n0 + c];
    }
    __syncthreads();
#pragma unroll
    for (int i = 0; i < 16; ++i) {
      int r = r0 + i * 4;
      cateWT[(size_t)(n0 + r) * 512 + k0 + c] = f2b(shmem[c * 65 + r]);
    }
  }
}

// ---------------- 256x256 MFMA GEMM, 8 waves, BK=64, 8-phase schedule -----------
// FROZEN round-3 kernel (72.0us, VGPR 116): XCD-chunked swizzle, 8-phase
// counted-vmcnt, MODE-1 sidx stash. No epilogue additions (round-5 lesson).
template <int MODE>
__global__ __launch_bounds__(512) void gemm256(
    const u16* __restrict__ A0, const u16* __restrict__ A1,
    const int* __restrict__ idx, const u16* __restrict__ embb,
    const u16* __restrict__ BT, const float* __restrict__ bias,
    u16* __restrict__ C, int K) {
  __shared__ u16 As[2][2][8192];
  __shared__ u16 Bs[2][2][8192];
  __shared__ int sidx[MODE == 1 ? 2048 : 4];
  const int tid = threadIdx.x;
  const int bid = blockIdx.x;
  const int chunk = gridDim.x >> 3;               // 32
  const int swz = (bid & 7) * chunk + (bid >> 3); // XCD-chunked, bijective
  const int row0 = (swz >> 2) * 256;
  const int col0 = (swz & 3) * 256;

  const int rr8 = tid >> 3;
  const int p8  = tid & 7;
  const int sl  = p8 ^ (rr8 & 7);

  const int l   = tid & 63;
  const int w   = tid >> 6;
  const int wrh = w >> 2;
  const int wcq = w & 3;
  const int hb  = wcq >> 1;
  const int rbb = (wcq & 1) * 64;
  const int lr  = l & 15;
  const int lk  = l >> 4;

  f32x4 acc[8][4];
#pragma unroll
  for (int m = 0; m < 8; ++m)
#pragma unroll
    for (int n = 0; n < 4; ++n) acc[m][n] = (f32x4){0.f, 0.f, 0.f, 0.f};

  const int nt = K >> 6;        // 8 (cate) or 32 (comb) -- always even
  const int nit = nt >> 1;

  if (MODE == 1) {              // stash all 256 rows x 8 k-chunk indices in LDS
    *(int4*)&sidx[tid * 4] = *(const int4*)&idx[row0 * 8 + tid * 4];
    __syncthreads();
  }

  auto stageA = [&](int t, int h) {               // one A half-tile: 2 loads
    const int k0 = t << 6;
    const int buf = t & 1;
#pragma unroll
    for (int i = 0; i < 2; ++i) {
      const u16* asrc;
      if (MODE == 1) {
        int id = sidx[(h * 128 + i * 64 + rr8) * 8 + (k0 >> 6)];
        asrc = embb + (size_t)id * 64 + sl * 8;
      } else {
        int ar = row0 + h * 128 + i * 64 + rr8;
        const u16* base = (k0 < 1024) ? A0 : A1;
        asrc = base + (size_t)ar * 1024 + (k0 & 1023) + sl * 8;
      }
      gload_lds16(asrc, &As[buf][h][i * 4096 + tid * 8]);
    }
  };
  auto stageB = [&](int t, int h) {               // one B half-tile: 2 loads
    const int k0 = t << 6;
    const int buf = t & 1;
#pragma unroll
    for (int i = 0; i < 2; ++i) {
      int br = col0 + h * 128 + i * 64 + rr8;
      gload_lds16(BT + (size_t)br * K + k0 + sl * 8,
                  &Bs[buf][h][i * 4096 + tid * 8]);
    }
  };

  bf16x8 bfr[4][2];
  auto loadB = [&](int buf) {                     // 8 ds_read_b128
#pragma unroll
    for (int n = 0; n < 4; ++n)
#pragma unroll
      for (int ks = 0; ks < 2; ++ks) {
        int rowb = rbb + n * 16 + lr;
        int ph = (ks * 4 + lk) ^ (lr & 7);
        bfr[n][ks] = *(const bf16x8*)&Bs[buf][hb][rowb * 64 + ph * 8];
      }
  };
  auto loadA = [&](bf16x8 (&af)[2][2], int buf, int q) {  // 4 ds_read_b128
#pragma unroll
    for (int mm = 0; mm < 2; ++mm)
#pragma unroll
      for (int ks = 0; ks < 2; ++ks) {
        int rowa = (q * 2 + mm) * 16 + lr;
        int ph = (ks * 4 + lk) ^ (lr & 7);
        af[mm][ks] = *(const bf16x8*)&As[buf][wrh][rowa * 64 + ph * 8];
      }
  };
  auto mfma_quad = [&](bf16x8 (&af)[2][2], int q) {       // 16 MFMA
    __builtin_amdgcn_s_setprio(1);
#pragma unroll
    for (int ks = 0; ks < 2; ++ks)
#pragma unroll
      for (int mm = 0; mm < 2; ++mm)
#pragma unroll
        for (int n = 0; n < 4; ++n)
          acc[q * 2 + mm][n] = __builtin_amdgcn_mfma_f32_16x16x32_bf16(
              af[mm][ks], bfr[n][ks], acc[q * 2 + mm][n], 0, 0, 0);
    __builtin_amdgcn_s_setprio(0);
  };

  // ---- prologue: tile0 A+B, tile1 B; wait tile0 (leave tile1-B in flight)
  stageA(0, 0); stageA(0, 1);
  stageB(0, 0); stageB(0, 1);
  stageB(1, 0); stageB(1, 1);
  asm volatile("s_waitcnt vmcnt(4)" ::: "memory");
  __builtin_amdgcn_s_barrier();

  for (int it = 0; it < nit; ++it) {
    const int T = it * 2;
    const bool more = (T + 2 < nt);     // also == (T+3 < nt) since nt even
    bf16x8 af[2][2];

    // -------- tile T (buf 0) --------
    loadB(0); loadA(af, 0, 0);
    stageA(T + 1, 0);
    __builtin_amdgcn_s_barrier();
    asm volatile("s_waitcnt lgkmcnt(0)" ::: "memory");
    mfma_quad(af, 0);
    __builtin_amdgcn_s_barrier();
    loadA(af, 0, 1);
    stageA(T + 1, 1);
    __builtin_amdgcn_s_barrier();
    asm volatile("s_waitcnt lgkmcnt(0)" ::: "memory");
    mfma_quad(af, 1);
    __builtin_amdgcn_s_barrier();
    loadA(af, 0, 2);
    if (more) stageB(T + 2, 0);
    __builtin_amdgcn_s_barrier();
    asm volatile("s_waitcnt lgkmcnt(0)" ::: "memory");
    mfma_quad(af, 2);
    __builtin_amdgcn_s_barrier();
    loadA(af, 0, 3);
    if (more) stageB(T + 2, 1);
    __builtin_amdgcn_s_barrier();
    asm volatile("s_waitcnt lgkmcnt(0)" ::: "memory");
    mfma_quad(af, 3);
    if (more) asm volatile("s_waitcnt vmcnt(4)" ::: "memory");
    else      asm volatile("s_waitcnt vmcnt(0)" ::: "memory");
    __builtin_amdgcn_s_barrier();

    // -------- tile T+1 (buf 1) --------
    loadB(1); loadA(af, 1, 0);
    if (more) stageA(T + 2, 0);
    __builtin_amdgcn_s_barrier();
    asm volatile("s_waitcnt lgkmcnt(0)" ::: "memory");
    mfma_quad(af, 0);
    __builtin_amdgcn_s_barrier();
    loadA(af, 1, 1);
    if (more) stageA(T + 2, 1);
    __builtin_amdgcn_s_barrier();
    asm volatile("s_waitcnt lgkmcnt(0)" ::: "memory");
    mfma_quad(af, 1);
    __builtin_amdgcn_s_barrier();
    loadA(af, 1, 2);
    if (more) stageB(T + 3, 0);
    __builtin_amdgcn_s_barrier();
    asm volatile("s_waitcnt lgkmcnt(0)" ::: "memory");
    mfma_quad(af, 2);
    __builtin_amdgcn_s_barrier();
    loadA(af, 1, 3);
    if (more) stageB(T + 3, 1);
    __builtin_amdgcn_s_barrier();
    asm volatile("s_waitcnt lgkmcnt(0)" ::: "memory");
    mfma_quad(af, 3);
    if (it + 1 < nit) {
      asm volatile("s_waitcnt vmcnt(4)" ::: "memory");
      __builtin_amdgcn_s_barrier();
    }
  }

  float bv_[4];
#pragma unroll
  for (int n = 0; n < 4; ++n) bv_[n] = bias[col0 + wcq * 64 + n * 16 + lr];
#pragma unroll
  for (int m = 0; m < 8; ++m) {
#pragma unroll
    for (int n = 0; n < 4; ++n) {
      int cc = col0 + wcq * 64 + n * 16 + lr;
#pragma unroll
      for (int q4 = 0; q4 < 4; ++q4) {
        int rr = row0 + wrh * 128 + m * 16 + lk * 4 + q4;
        C[(size_t)rr * 1024 + cc] = f2b(acc[m][n][q4] + bv_[n]);
      }
    }
  }
}

// ---------------- In-place LayerNorm body (used by mid_k for X1) ----------------
__device__ __forceinline__ void ln_body(u16* __restrict__ buf,
                                        const float* __restrict__ g,
                                        const float* __restrict__ b, int relu,
                                        int blk, int tid) {
  int lane = tid & 63, wave = tid >> 6;
  size_t row = (size_t)blk * 4 + wave;
  u16* p = buf + row * 1024 + lane * 16;
  uint4 u0 = *(uint4*)p;
  uint4 u1 = *(uint4*)(p + 8);
  float x[16];
#pragma unroll
  for (int i = 0; i < 4; ++i) {
    unsigned int w0 = ((unsigned int*)&u0)[i];
    unsigned int w1 = ((unsigned int*)&u1)[i];
    x[2 * i]     = b2f((u16)(w0 & 0xffff));
    x[2 * i + 1] = b2f((u16)(w0 >> 16));
    x[8 + 2 * i]     = b2f((u16)(w1 & 0xffff));
    x[8 + 2 * i + 1] = b2f((u16)(w1 >> 16));
  }
  float s = 0.f, s2 = 0.f;
#pragma unroll
  for (int i = 0; i < 16; ++i) { s += x[i]; s2 += x[i] * x[i]; }
#pragma unroll
  for (int off = 32; off; off >>= 1) { s += __shfl_xor(s, off); s2 += __shfl_xor(s2, off); }
  float mean = s * (1.f / 1024.f);
  float var = s2 * (1.f / 1024.f) - mean * mean;
  float rs = rsqrtf(var + EPS);
  float y[16];
#pragma unroll
  for (int q = 0; q < 4; ++q) {
    float4 gv = *(const float4*)(g + lane * 16 + q * 4);
    float4 bv = *(const float4*)(b + lane * 16 + q * 4);
    y[4 * q]     = (x[4 * q]     - mean) * rs * gv.x + bv.x;
    y[4 * q + 1] = (x[4 * q + 1] - mean) * rs * gv.y + bv.y;
    y[4 * q + 2] = (x[4 * q + 2] - mean) * rs * gv.z + bv.z;
    y[4 * q + 3] = (x[4 * q + 3] - mean) * rs * gv.w + bv.w;
  }
  if (relu)
#pragma unroll
    for (int i = 0; i < 16; ++i) y[i] = fmaxf(y[i], 0.f);
  uint4 o0, o1;
#pragma unroll
  for (int i = 0; i < 4; ++i) {
    ((unsigned int*)&o0)[i] = (unsigned int)f2b(y[2 * i]) | ((unsigned int)f2b(y[2 * i + 1]) << 16);
    ((unsigned int*)&o1)[i] = (unsigned int)f2b(y[8 + 2 * i]) | ((unsigned int)f2b(y[8 + 2 * i + 1]) << 16);
  }
  *(uint4*)p = o0;
  *(uint4*)(p + 8) = o1;
}

// ---------------- cont path body (BN -> Linear(8->1024) -> LN -> ReLU) ----------
__device__ __forceinline__ void cont_body(const float* __restrict__ cx,
                                          const float* __restrict__ part_bn,
                                          const float* __restrict__ bn_g,
                                          const float* __restrict__ bn_b,
                                          const float* __restrict__ W,
                                          const float* __restrict__ cb,
                                          const float* __restrict__ g,
                                          const float* __restrict__ bb,
                                          u16* __restrict__ out,
                                          int row0, int tid) {
  __shared__ float sp[4][16];
  __shared__ float tt[16];
  __shared__ float ab[2][8];
  __shared__ float xn[8][8];
  __shared__ float rr1[4][8], rr2[4][8];

  if (tid < 64) {
    int f = tid & 15, qd = tid >> 4;
    float s = 0.f;
    for (int j = qd * 16; j < qd * 16 + 16; ++j) s += part_bn[j * 16 + f];
    sp[qd][f] = s;
  }
  __syncthreads();
  if (tid < 16) tt[tid] = sp[0][tid] + sp[1][tid] + sp[2][tid] + sp[3][tid];
  __syncthreads();
  if (tid < 8) {
    float mu = tt[tid] * (1.f / 16384.f);
    float var = tt[8 + tid] * (1.f / 16384.f) - mu * mu;
    float a = rsqrtf(var + EPS) * bn_g[tid];
    ab[0][tid] = a;
    ab[1][tid] = bn_b[tid] - mu * a;
  }
  __syncthreads();
  if (tid < 64) {
    int r = tid >> 3, f = tid & 7;
    xn[r][f] = ab[0][f] * cx[(row0 + r) * 8 + f] + ab[1][f];
  }
  __syncthreads();

  int c = tid * 4;
  float4 cbv = *(const float4*)(cb + c);
  float acc[8][4];
#pragma unroll
  for (int r = 0; r < 8; ++r) {
    acc[r][0] = cbv.x; acc[r][1] = cbv.y; acc[r][2] = cbv.z; acc[r][3] = cbv.w;
  }
  for (int k = 0; k < 8; ++k) {
    float4 w4 = *(const float4*)(W + k * 1024 + c);
#pragma unroll
    for (int r = 0; r < 8; ++r) {
      float xv = xn[r][k];
      acc[r][0] = fmaf(xv, w4.x, acc[r][0]);
      acc[r][1] = fmaf(xv, w4.y, acc[r][1]);
      acc[r][2] = fmaf(xv, w4.z, acc[r][2]);
      acc[r][3] = fmaf(xv, w4.w, acc[r][3]);
    }
  }
  float s1[8], s2[8];
#pragma unroll
  for (int r = 0; r < 8; ++r) {
    s1[r] = acc[r][0] + acc[r][1] + acc[r][2] + acc[r][3];
    s2[r] = acc[r][0] * acc[r][0] + acc[r][1] * acc[r][1] +
            acc[r][2] * acc[r][2] + acc[r][3] * acc[r][3];
  }
#pragma unroll
  for (int off = 32; off; off >>= 1)
#pragma unroll
    for (int r = 0; r < 8; ++r) {
      s1[r] += __shfl_down(s1[r], off);
      s2[r] += __shfl_down(s2[r], off);
    }
  int lane = tid & 63, wv = tid >> 6;
  if (lane == 0)
#pragma unroll
    for (int r = 0; r < 8; ++r) { rr1[wv][r] = s1[r]; rr2[wv][r] = s2[r]; }
  __syncthreads();
  float4 gv = *(const float4*)(g + c);
  float4 bv = *(const float4*)(bb + c);
#pragma unroll
  for (int r = 0; r < 8; ++r) {
    float ss = rr1[0][r] + rr1[1][r] + rr1[2][r] + rr1[3][r];
    float qq = rr2[0][r] + rr2[1][r] + rr2[2][r] + rr2[3][r];
    float mean = ss * (1.f / 1024.f);
    float var = qq * (1.f / 1024.f) - mean * mean;
    float rs = rsqrtf(var + EPS);
    float y0 = fmaxf((acc[r][0] - mean) * rs * gv.x + bv.x, 0.f);
    float y1 = fmaxf((acc[r][1] - mean) * rs * gv.y + bv.y, 0.f);
    float y2 = fmaxf((acc[r][2] - mean) * rs * gv.z + bv.z, 0.f);
    float y3 = fmaxf((acc[r][3] - mean) * rs * gv.w + bv.w, 0.f);
    ushort4 o; o.x = f2b(y0); o.y = f2b(y1); o.z = f2b(y2); o.w = f2b(y3);
    *(ushort4*)(out + (size_t)(row0 + r) * 1024 + c) = o;
  }
}

// ---------------- fused mid dispatch ---------------------------------------------
// grid: [0,4096) ln(X1) | [4096,4608) combWT | [4608,4672) wvog | [4672,6720) cont
//       | 6720 bc = bv.Wo[:,1023] + bo[1023]
__global__ __launch_bounds__(256) void mid_k(
    u16* __restrict__ X1, const float* __restrict__ cate_g,
    const float* __restrict__ cate_bb,
    const float* __restrict__ comb_W, u16* __restrict__ combWT,
    const float* __restrict__ Wv, const float* __restrict__ Wo,
    const float* __restrict__ comb_g, const float* __restrict__ comb_bbv,
    u16* __restrict__ wvob_hi, u16* __restrict__ wvob_lo,
    float* __restrict__ Swg, float* __restrict__ Swb,
    const float* __restrict__ bv, const float* __restrict__ bo,
    float* __restrict__ bc,
    const float* __restrict__ cx, const float* __restrict__ part_bn,
    const float* __restrict__ bn_g, const float* __restrict__ bn_b,
    const float* __restrict__ cont_W, const float* __restrict__ cont_b,
    const float* __restrict__ cont_g, const float* __restrict__ cont_bb,
    u16* __restrict__ X2) {
  __shared__ float shmem[64 * 65];
  const int bid = blockIdx.x, tid = threadIdx.x;
  if (bid < 4096) {                      // LN(X1) + ReLU
    ln_body(X1, cate_g, cate_bb, 1, bid, tid);
    return;
  }
  if (bid < 4608) {                      // combWT transpose fp32->bf16 (K=2048)
    int local = bid - 4096;
    int n0 = (local & 15) * 64, k0 = (local >> 4) * 64;
    int c = tid & 63, r0 = tid >> 6;
#pragma unroll
    for (int i = 0; i < 16; ++i) {
      int r = r0 + i * 4;
      shmem[r * 65 + c] = comb_W[(size_t)(k0 + r) * 1024 + n0 + c];
    }
    __syncthreads();
#pragma unroll
    for (int i = 0; i < 16; ++i) {
      int r = r0 + i * 4;
      combWT[(size_t)(n0 + r) * 2048 + k0 + c] = f2b(shmem[c * 65 + r]);
    }
    return;
  }
  if (bid < 4672) {                      // wvog (bf16 hi+lo), Swg/Swb
    int local = bid - 4608;
    int h = local >> 2, jc = local & 3;
    if (tid < 64) shmem[tid] = Wo[(size_t)(h * 64 + tid) * 1024 + 1023];
    __syncthreads();
    int j = jc * 256 + tid;
    const float* vr = Wv + (size_t)j * 1024 + h * 64;
    float s = 0.f;
    for (int d4 = 0; d4 < 64; d4 += 4) {
      float4 w4 = *(const float4*)(vr + d4);
      s = fmaf(w4.x, shmem[d4], s);
      s = fmaf(w4.y, shmem[d4 + 1], s);
      s = fmaf(w4.z, shmem[d4 + 2], s);
      s = fmaf(w4.w, shmem[d4 + 3], s);
    }
    float sg_ = s * comb_g[j];
    u16 hi = f2b(sg_);
    float lo = sg_ - b2f(hi);
    wvob_hi[h * 1024 + j] = hi;
    wvob_lo[h * 1024 + j] = f2b(lo);
    float swgp = sg_;
    float swbp = s * comb_bbv[j];
#pragma unroll
    for (int off = 32; off; off >>= 1) {
      swgp += __shfl_down(swgp, off);
      swbp += __shfl_down(swbp, off);
    }
    int lane = tid & 63, wv = tid >> 6;
    if (lane == 0) { shmem[64 + wv] = swgp; shmem[68 + wv] = swbp; }
    __syncthreads();
    if (tid == 0) {
      atomicAdd(&Swg[h], shmem[64] + shmem[65] + shmem[66] + shmem[67]);
      atomicAdd(&Swb[h], shmem[68] + shmem[69] + shmem[70] + shmem[71]);
    }
    return;
  }
  if (bid < 6720) {                      // cont path -> X2
    int row0 = (bid - 4672) * 8;
    cont_body(cx, part_bn, bn_g, bn_b, cont_W, cont_b, cont_g, cont_bb, X2,
              row0, tid);
    return;
  }
  {                                      // bc = bv . Wo[:,1023] + bo[1023]
    float s = 0.f;
    for (int i = tid; i < 1024; i += 256)
      s = fmaf(bv[i], Wo[(size_t)i * 1024 + 1023], s);
#pragma unroll
    for (int off = 32; off; off >>= 1) s += __shfl_down(s, off);
    int lane = tid & 63, wv = tid >> 6;
    if (lane == 0) shmem[wv] = s;
    __syncthreads();
    if (tid == 0) bc[0] = shmem[0] + shmem[1] + shmem[2] + shmem[3] + bo[1023];
  }
}

// ---------------- Q projection partials, grid 256 = (colblk 0..63, kq4 0..3) ----
// Each block: stage+LN its 16 rows (stats recomputed redundantly, L2-hot),
// compute partial Q over its 256-k quarter, write qpart[kq4]. bq folded into
// partial 0. kq_k sums the 4 partials. Stats loop vectorized (ushort4).
__global__ __launch_bounds__(256) void qproj_k(const u16* __restrict__ x,
                                               const float* __restrict__ g,
                                               const float* __restrict__ bb,
                                               const float* __restrict__ Wq,
                                               const float* __restrict__ bq,
                                               float* __restrict__ qpart) {
  __shared__ u16 xs[16][1024];
  __shared__ float part[16][16][16];
  __shared__ float ps1[16][16], ps2[16][16];
  __shared__ float sm[16], sr[16];
  int tid = threadIdx.x;
  int cb = blockIdx.x >> 2, kq4 = blockIdx.x & 3;
  // stage raw rows (b, 1023)
  for (int i = tid; i < 4096; i += 256) {
    int b = i >> 8, off = (i & 255) * 4;
    *(ushort4*)&xs[b][off] =
        *(const ushort4*)(x + ((size_t)(b * 1024 + 1023)) * 1024 + off);
  }
  __syncthreads();
  // per-row LN stats: 16 threads/row, 64 cols each (ushort4-vectorized reads)
  {
    int b = tid >> 4, seg = tid & 15;
    float s = 0.f, s2 = 0.f;
    for (int k4 = seg * 64; k4 < seg * 64 + 64; k4 += 4) {
      ushort4 u = *(const ushort4*)&xs[b][k4];
      float a0 = b2f(u.x), a1 = b2f(u.y), a2 = b2f(u.z), a3 = b2f(u.w);
      s += a0 + a1 + a2 + a3;
      s2 += a0 * a0 + a1 * a1 + a2 * a2 + a3 * a3;
    }
    ps1[b][seg] = s;
    ps2[b][seg] = s2;
  }
  __syncthreads();
  if (tid < 16) {
    float s = 0.f, s2 = 0.f;
#pragma unroll
    for (int j = 0; j < 16; ++j) { s += ps1[tid][j]; s2 += ps2[tid][j]; }
    float mean = s * (1.f / 1024.f);
    float var = s2 * (1.f / 1024.f) - mean * mean;
    sm[tid] = mean;
    sr[tid] = rsqrtf(var + EPS);
  }
  __syncthreads();
  // normalize in place
  for (int i = tid; i < 4096; i += 256) {
    int b = i >> 8, off = (i & 255) * 4;
    ushort4 u = *(ushort4*)&xs[b][off];
    float4 gv = *(const float4*)(g + off);
    float4 bvv = *(const float4*)(bb + off);
    float m = sm[b], r = sr[b];
    ushort4 o;
    o.x = f2b((b2f(u.x) - m) * r * gv.x + bvv.x);
    o.y = f2b((b2f(u.y) - m) * r * gv.y + bvv.y);
    o.z = f2b((b2f(u.z) - m) * r * gv.z + bvv.z);
    o.w = f2b((b2f(u.w) - m) * r * gv.w + bvv.w);
    *(ushort4*)&xs[b][off] = o;
  }
  __syncthreads();
  int c = tid & 15;
  int col = cb * 16 + c;
  int kq = tid >> 4;
  float acc[16];
#pragma unroll
  for (int b = 0; b < 16; ++b) acc[b] = 0.f;
  int kbase = kq4 * 256 + kq * 16;
  for (int k = kbase; k < kbase + 16; ++k) {
    float wv = Wq[(size_t)k * 1024 + col];
#pragma unroll
    for (int b = 0; b < 16; ++b) acc[b] = fmaf(b2f(xs[b][k]), wv, acc[b]);
  }
#pragma unroll
  for (int b = 0; b < 16; ++b) part[kq][b][c] = acc[b];
  __syncthreads();
  {
    int b = tid >> 4, cc = tid & 15;
    float s = 0.f;
#pragma unroll
    for (int j = 0; j < 16; ++j) s += part[j][b][cc];
    if (kq4 == 0) s += bq[cb * 16 + cc];
    qpart[kq4 * 16384 + b * 1024 + cb * 16 + cc] = s;
  }
}

// ---------------- qtg[b,h,j] = g_j * (Wk[:,h*64..] @ Q)[j]; bkq, Sg, Sb ----------
// grid 256 = (h 0..15, jc 0..3, bg 0..3): batch split x4 (same summand
// partition per (b,h) atomic -- one add per jc -- values identical).
__global__ __launch_bounds__(256) void kq_k(const float* __restrict__ Wk,
                                            const float* __restrict__ bk,
                                            const float* __restrict__ qpart,
                                            const float* __restrict__ g,
                                            const float* __restrict__ bb,
                                            u16* __restrict__ qtb,
                                            float* __restrict__ bkq,
                                            float* __restrict__ Sg,
                                            float* __restrict__ Sb) {
  int h = blockIdx.x >> 4, jc = (blockIdx.x >> 2) & 3, bg = blockIdx.x & 3;
  int tid = threadIdx.x;
  __shared__ float Qs[4][64];
  __shared__ float rg[4][4], rb[4][4];
  if (tid < 256) {                       // 256 elements: one per thread
    int bl = tid >> 6, d = tid & 63;
    int o = (bg * 4 + bl) * 1024 + h * 64 + d;
    Qs[bl][d] = qpart[o] + qpart[16384 + o] + qpart[32768 + o] + qpart[49152 + o];
  }
  __syncthreads();
  int j = jc * 256 + tid;
  float acc[4];
#pragma unroll
  for (int bl = 0; bl < 4; ++bl) acc[bl] = 0.f;
  const float* wr = Wk + (size_t)j * 1024 + h * 64;
  for (int d4 = 0; d4 < 64; d4 += 4) {
    float4 w4 = *(const float4*)(wr + d4);
#pragma unroll
    for (int bl = 0; bl < 4; ++bl) {
      acc[bl] = fmaf(w4.x, Qs[bl][d4], acc[bl]);
      acc[bl] = fmaf(w4.y, Qs[bl][d4 + 1], acc[bl]);
      acc[bl] = fmaf(w4.z, Qs[bl][d4 + 2], acc[bl]);
      acc[bl] = fmaf(w4.w, Qs[bl][d4 + 3], acc[bl]);
    }
  }
  float gj = g[j], bbj = bb[j];
  float sgp[4], sbp[4];
#pragma unroll
  for (int bl = 0; bl < 4; ++bl) {
    int b = bg * 4 + bl;
    u16 qg = f2b(acc[bl] * gj);
    qtb[((size_t)b * 16 + h) * 1024 + j] = qg;
    sgp[bl] = b2f(qg);           // match what the MFMA will see
    sbp[bl] = acc[bl] * bbj;
  }
#pragma unroll
  for (int off = 32; off; off >>= 1)
#pragma unroll
    for (int bl = 0; bl < 4; ++bl) {
      sgp[bl] += __shfl_down(sgp[bl], off);
      sbp[bl] += __shfl_down(sbp[bl], off);
    }
  int lane = tid & 63, wv = tid >> 6;
  if (lane == 0)
#pragma unroll
    for (int bl = 0; bl < 4; ++bl) { rg[wv][bl] = sgp[bl]; rb[wv][bl] = sbp[bl]; }
  __syncthreads();
  if (tid < 4) {
    int bl = tid, b = bg * 4 + bl;
    atomicAdd(&Sg[b * 16 + h], rg[0][bl] + rg[1][bl] + rg[2][bl] + rg[3][bl]);
    atomicAdd(&Sb[b * 16 + h], rb[0][bl] + rb[1][bl] + rb[2][bl] + rb[3][bl]);
  }
  if (jc == 0 && tid < 4) {
    int bl = tid, b = bg * 4 + bl;
    float s = 0.f;
    for (int d = 0; d < 64; ++d) s = fmaf(bk[h * 64 + d], Qs[bl][d], s);
    bkq[b * 16 + h] = s;
  }
}

// ---------------- scores + y, grid 1024 = (b, 16-key group); k split over waves --
// Each of 4 waves covers the SAME 16 keys over its 256-k quarter; partial
// acc/acy/as1/as2 LDS-reduced; wave 0 does the LN-folded epilogue. Row stats
// via MFMA: Sx = mfma(afr,ones) (row-sum lands at own output slot), Sx2 =
// Gram diag mfma(afr,afr) + 1 shuffle.
__global__ __launch_bounds__(256) void score_k(
    const u16* __restrict__ x, const u16* __restrict__ qtb,
    const float* __restrict__ bkq, const int* __restrict__ mask,
    const u16* __restrict__ whi, const u16* __restrict__ wlo,
    const float* __restrict__ Sg, const float* __restrict__ Sb,
    const float* __restrict__ Swg, const float* __restrict__ Swb,
    float* __restrict__ sc, float* __restrict__ y) {
  int b = blockIdx.x >> 6, kg = blockIdx.x & 63;
  int tid = threadIdx.x;
  int l = tid & 63, w = tid >> 6;     // w = k-quarter
  int keybase = kg * 16;
  int lr = l & 15, ls = l >> 4;
  int masked = (mask[b * 1024 + 1023] == 0);

  bf16x8 ones;
#pragma unroll
  for (int j = 0; j < 8; ++j) ones[j] = (short)0x3F80;  // bf16 1.0

  f32x4 acc = (f32x4){0.f, 0.f, 0.f, 0.f};
  f32x4 acy = (f32x4){0.f, 0.f, 0.f, 0.f};
  f32x4 as1 = (f32x4){0.f, 0.f, 0.f, 0.f};
  f32x4 as2 = (f32x4){0.f, 0.f, 0.f, 0.f};
  const u16* xb = x + (size_t)b * 1024 * 1024;
  const u16* qb = qtb + (size_t)b * 16 * 1024;
  const int k0beg = w * 256;
  for (int k0 = k0beg; k0 < k0beg + 256; k0 += 32) {
    bf16x8 bfr = *(const bf16x8*)&qb[(size_t)lr * 1024 + k0 + ls * 8];
    bf16x8 bh  = *(const bf16x8*)&whi[(size_t)lr * 1024 + k0 + ls * 8];
    bf16x8 bl  = *(const bf16x8*)&wlo[(size_t)lr * 1024 + k0 + ls * 8];
    bf16x8 afr = *(const bf16x8*)&xb[(size_t)(keybase + lr) * 1024 + k0 + ls * 8];
    acc = __builtin_amdgcn_mfma_f32_16x16x32_bf16(afr, bfr, acc, 0, 0, 0);
    acy = __builtin_amdgcn_mfma_f32_16x16x32_bf16(afr, bh, acy, 0, 0, 0);
    acy = __builtin_amdgcn_mfma_f32_16x16x32_bf16(afr, bl, acy, 0, 0, 0);
    as1 = __builtin_amdgcn_mfma_f32_16x16x32_bf16(afr, ones, as1, 0, 0, 0);
    as2 = __builtin_amdgcn_mfma_f32_16x16x32_bf16(afr, afr, as2, 0, 0, 0);
  }

  __shared__ float red[3][64][16];
  if (w > 0) {
    float* r = red[w - 1][l];
#pragma unroll
    for (int q = 0; q < 4; ++q) {
      r[q] = acc[q]; r[4 + q] = acy[q]; r[8 + q] = as1[q]; r[12 + q] = as2[q];
    }
  }
  __syncthreads();
  if (w == 0) {
#pragma unroll
    for (int i = 0; i < 3; ++i) {
      const float* r = red[i][l];
#pragma unroll
      for (int q = 0; q < 4; ++q) {
        acc[q] += r[q]; acy[q] += r[4 + q]; as1[q] += r[8 + q]; as2[q] += r[12 + q];
      }
    }
    int h = lr;
    float bq_  = bkq[b * 16 + h];
    float Sgv  = Sg[b * 16 + h];
    float Sbv  = Sb[b * 16 + h];
    float Swgv = Swg[h];
    float Swbv = Swb[h];
#pragma unroll
    for (int q = 0; q < 4; ++q) {
      int key = keybase + ls * 4 + q;
      float s1 = as1[q];
      float s2 = __shfl(as2[q], ls * 4 + q + 16 * ls);
      float mean = s1 * (1.f / 1024.f);
      float var  = s2 * (1.f / 1024.f) - mean * mean;
      float rs   = rsqrtf(var + EPS);
      float sraw = rs * acc[q] - rs * mean * Sgv + Sbv + bq_;
      float v = masked ? 0.f : sraw * 0.125f;
      sc[((size_t)b * 16 + h) * 1024 + key] = v;
      y[((size_t)b * 16 + h) * 1024 + key] =
          rs * acy[q] - rs * mean * Swgv + Swbv;
    }
  }
}

// ---------------- fin: softmax(sc[bh]) . y[bh] -> atomicAdd out[b] (+bc once) ----
__global__ __launch_bounds__(256) void fin_k(const float* __restrict__ sc,
                                             const float* __restrict__ y,
                                             const float* __restrict__ bc,
                                             float* __restrict__ out) {
  int bh = blockIdx.x, tid = threadIdx.x;
  float4 v = ((const float4*)(sc + (size_t)bh * 1024))[tid];
  float m = fmaxf(fmaxf(v.x, v.y), fmaxf(v.z, v.w));
#pragma unroll
  for (int off = 32; off; off >>= 1) m = fmaxf(m, __shfl_down(m, off));
  __shared__ float rm[4], rs_[4], rd_[4];
  int lane = tid & 63, wv = tid >> 6;
  if (lane == 0) rm[wv] = m;
  __syncthreads();
  m = fmaxf(fmaxf(rm[0], rm[1]), fmaxf(rm[2], rm[3]));
  float e0 = expf(v.x - m), e1 = expf(v.y - m), e2 = expf(v.z - m), e3 = expf(v.w - m);
  float4 yv = ((const float4*)(y + (size_t)bh * 1024))[tid];
  float s = e0 + e1 + e2 + e3;
  float d = e0 * yv.x + e1 * yv.y + e2 * yv.z + e3 * yv.w;
#pragma unroll
  for (int off = 32; off; off >>= 1) {
    s += __shfl_down(s, off);
    d += __shfl_down(d, off);
  }
  if (lane == 0) { rs_[wv] = s; rd_[wv] = d; }
  __syncthreads();
  if (tid == 0) {
    float Z = rs_[0] + rs_[1] + rs_[2] + rs_[3];
    float D = rd_[0] + rd_[1] + rd_[2] + rd_[3];
    float add = D / Z;
    if ((bh & 15) == 0) add += bc[0];
    atomicAdd(&out[bh >> 4], add);
  }
}

extern "C" void kernel_launch(void* const* d_in, const int* in_sizes, int n_in,
                              void* d_out, int out_size, void* d_ws, size_t ws_size,
                              hipStream_t stream) {
  const int*   cate_x  = (const int*)d_in[0];
  const float* cont_x  = (const float*)d_in[1];
  const int*   mask    = (const int*)d_in[2];
  const float* emb     = (const float*)d_in[3];
  const float* cate_W  = (const float*)d_in[4];
  const float* cate_b  = (const float*)d_in[5];
  const float* cate_g  = (const float*)d_in[6];
  const float* cate_bb = (const float*)d_in[7];
  const float* bn_g    = (const float*)d_in[8];
  const float* bn_b    = (const float*)d_in[9];
  const float* cont_W  = (const float*)d_in[10];
  const float* cont_b  = (const float*)d_in[11];
  const float* cont_g  = (const float*)d_in[12];
  const float* cont_bb = (const float*)d_in[13];
  const float* Wq = (const float*)d_in[18]; const float* bq = (const float*)d_in[19];
  const float* Wk = (const float*)d_in[20]; const float* bk = (const float*)d_in[21];
  const float* Wv = (const float*)d_in[22]; const float* bv = (const float*)d_in[23];
  const float* Wo = (const float*)d_in[24]; const float* bo = (const float*)d_in[25];
  const float* comb_W  = (const float*)d_in[14];
  const float* comb_b  = (const float*)d_in[15];
  const float* comb_g  = (const float*)d_in[16];
  const float* comb_bb = (const float*)d_in[17];
  float* out = (float*)d_out;

  char* w = (char*)d_ws;
  float* part_bn = (float*)(w + 256);         // 64*16 f32 = 4KB
  u16* embb      = (u16*)(w + 131328);        // 1.25MB
  u16* cateWT    = (u16*)(w + 1411328);       // 1MB
  u16* combWT    = (u16*)(w + 2459904);       // 4MB
  float* sc      = (float*)(w + 6654208);     // 1MB scores
  u16*   qtb     = (u16*)(w + 7702784);       // 512KB
  float* bkq     = (float*)(w + 8292608);     // 1KB
  float* ybuf    = (float*)(w + 8388608);     // 1MB y
  u16* wvob_hi   = (u16*)(w + 9437184);       // 32KB
  u16* wvob_lo   = (u16*)(w + 9469952);       // 32KB
  float* qpart   = (float*)(w + 9506816);     // 256KB Q partials [4][16K]
  float* Sall    = (float*)(w + 10162176);    // Sg[256]|Sb[256]|Swg[16]|Swb[16]|bc
  float* Sg      = Sall;
  float* Sb      = Sall + 256;
  float* Swg     = Sall + 512;
  float* Swb     = Sall + 528;
  float* bc      = Sall + 552;                // 1 f32 (written by mid_k)
  u16* X1        = (u16*)(w + 10848512);      // 32MB
  u16* X2        = X1 + (size_t)16777216;     // 32MB
  u16* xb        = X2 + (size_t)16777216;     // 32MB (RAW gemm2 output, pre-LN)

  // preprocessing (zero out+Sall | BN partials | embconv | cateWT)
  prep_k<<<818, 256, 0, stream>>>(cont_x, part_bn, out, Sall, emb, embb,
                                  cate_W, cateWT);

  // cate: gathered-emb GEMM (K=512) -> X1
  gemm256<1><<<256, 512, 0, stream>>>(nullptr, nullptr, cate_x, embb, cateWT,
                                      cate_b, X1, 512);
  // fused: LN+ReLU(X1) | combWT | wvog hi/lo + Swg/Swb | cont -> X2 | bc
  mid_k<<<6721, 256, 0, stream>>>(X1, cate_g, cate_bb, comb_W, combWT, Wv, Wo,
                                  comb_g, comb_bb, wvob_hi, wvob_lo, Swg, Swb,
                                  bv, bo, bc, cont_x, part_bn, bn_g, bn_b,
                                  cont_W, cont_b, cont_g, cont_bb, X2);
  // combine: concat GEMM (K=2048) -> xb RAW (pre-LN)
  gemm256<2><<<256, 512, 0, stream>>>(X1, X2, nullptr, nullptr, combWT,
                                      comb_b, xb, 2048);

  // folded attention path (LN applied algebraically; stats computed in-kernel)
  qproj_k<<<256, 256, 0, stream>>>(xb, comb_g, comb_bb, Wq, bq, qpart);
  kq_k<<<256, 256, 0, stream>>>(Wk, bk, qpart, comb_g, comb_bb, qtb, bkq, Sg, Sb);
  score_k<<<1024, 256, 0, stream>>>(xb, qtb, bkq, mask, wvob_hi, wvob_lo,
                                    Sg, Sb, Swg, Swb, sc, ybuf);
  fin_k<<<256, 256, 0, stream>>>(sc, ybuf, bc, out);
}